// Round 1
// baseline (482.056 us; speedup 1.0000x reference)
//
#include <hip/hip_runtime.h>
#include <cstdint>
#include <cstddef>

// ---------------- helpers ----------------
__device__ __forceinline__ void fma4(float4& acc, float s, const float4& w){
  acc.x = fmaf(s, w.x, acc.x);
  acc.y = fmaf(s, w.y, acc.y);
  acc.z = fmaf(s, w.z, acc.z);
  acc.w = fmaf(s, w.w, acc.w);
}

// ---------------- CSR build ----------------
__global__ void k_hist(const int* __restrict__ dst, int E, int* __restrict__ cnt){
  int i = blockIdx.x * blockDim.x + threadIdx.x;
  int stride = gridDim.x * blockDim.x;
  for (; i < E; i += stride) atomicAdd(&cnt[dst[i]], 1);
}

__global__ __launch_bounds__(1024) void k_scan(const int* __restrict__ cnt, int n,
                                               int* __restrict__ row_ptr,
                                               int* __restrict__ fill,
                                               float* __restrict__ inv_cnt){
  __shared__ int wsum[16];
  __shared__ int carry_s;
  const int t = threadIdx.x;
  const int lane = t & 63;
  const int wv = t >> 6;
  if (t == 0) carry_s = 0;
  __syncthreads();
  for (int base = 0; base < n; base += 1024){
    int i = base + t;
    int v = (i < n) ? cnt[i] : 0;
    int x = v;
    #pragma unroll
    for (int off = 1; off < 64; off <<= 1){
      int y = __shfl_up(x, off);
      if (lane >= off) x += y;
    }
    if (lane == 63) wsum[wv] = x;
    __syncthreads();
    if (wv == 0 && lane < 16){
      int s = wsum[lane];
      #pragma unroll
      for (int off = 1; off < 16; off <<= 1){
        int y = __shfl_up(s, off);
        if (lane >= off) s += y;
      }
      wsum[lane] = s;
    }
    __syncthreads();
    int waveoff = (wv == 0) ? 0 : wsum[wv - 1];
    int carry = carry_s;
    int incl = carry + waveoff + x;
    if (i < n){
      int excl = incl - v;
      row_ptr[i] = excl;
      fill[i] = excl;
      inv_cnt[i] = 1.0f / (float)((v > 0) ? v : 1);
    }
    __syncthreads();
    if (t == 1023) carry_s = incl;
    __syncthreads();
  }
  if (t == 0) row_ptr[n] = carry_s;
}

__global__ void k_fill(const int* __restrict__ src, const int* __restrict__ dst, int E,
                       int* __restrict__ fill, int* __restrict__ csr){
  int i = blockIdx.x * blockDim.x + threadIdx.x;
  int stride = gridDim.x * blockDim.x;
  for (; i < E; i += stride){
    int d = dst[i];
    int pos = atomicAdd(&fill[d], 1);
    csr[pos] = src[i];
  }
}

// ---------------- mean aggregation (gather) ----------------
// one wave per node, float2 per lane (128 floats/row)
__global__ __launch_bounds__(256) void k_agg(const float* __restrict__ feat,
                                             const int* __restrict__ csr,
                                             const int* __restrict__ row_ptr,
                                             const float* __restrict__ inv_cnt,
                                             float* __restrict__ outb, int n){
  const int lane = threadIdx.x & 63;
  const int node = (blockIdx.x * blockDim.x + threadIdx.x) >> 6;
  if (node >= n) return;
  const int beg = row_ptr[node];
  const int end = row_ptr[node + 1];
  float ax = 0.f, ay = 0.f;
  for (int j = beg; j < end; ++j){
    const int s = csr[j];
    const float2 v = *(const float2*)&feat[(size_t)s * 128 + lane * 2];
    ax += v.x; ay += v.y;
  }
  const float ic = inv_cnt[node];
  float2 o; o.x = ax * ic; o.y = ay * ic;
  *(float2*)&outb[(size_t)node * 128 + lane * 2] = o;
}

// ---------------- weight pack: Wc[k][c], k-major ----------------
__global__ void k_wc(const float* __restrict__ wl, const float* __restrict__ wr,
                     float* __restrict__ wc){
  int id = blockIdx.x * 256 + threadIdx.x;
  if (id >= 256 * 128) return;
  int k = id >> 7, c = id & 127;
  wc[id] = (k < 128) ? wl[c * 128 + k] : wr[c * 128 + (k - 128)];
}

// ---------------- fused GEMM: out = prelu([A0|A1] @ Wc + b) ----------------
// 32-node tile/block, 256 threads, 4 nodes x 4 cols per thread
__global__ __launch_bounds__(256) void k_gemm(const float* __restrict__ A0,   // [n][128] -> k 0..127
                                              const float* __restrict__ A1,   // [n][128] -> k 128..255
                                              const float* __restrict__ Wc,   // [256][128]
                                              const float* __restrict__ bias, // [128]
                                              const float* __restrict__ alpha_p,
                                              float* __restrict__ out,        // [n][128]
                                              int n){
  __shared__ float aT[32][264];   // [node][k], pad 264 (1056B rows, 16B aligned)
  const int t = threadIdx.x;
  const int nb = blockIdx.x * 32;
  const int tcol = t & 31;   // k-quad
  const int trow = t >> 5;   // 0..7

  // stage A-tile: fully coalesced global reads, contiguous LDS b128 writes
  #pragma unroll
  for (int half = 0; half < 2; ++half){
    const float* __restrict__ src = half ? A1 : A0;
    #pragma unroll
    for (int rr = 0; rr < 4; ++rr){
      int r = rr * 8 + trow;
      int node = nb + r; if (node > n - 1) node = n - 1;
      const float4 v = *(const float4*)&src[(size_t)node * 128 + tcol * 4];
      *(float4*)&aT[r][half * 128 + tcol * 4] = v;
    }
  }
  __syncthreads();

  const int c_t = t & 31;   // col quad: cols c_t*4..+3
  const int n_t = t >> 5;   // node quad: nodes n_t*4..+3
  float4 acc0 = {0,0,0,0}, acc1 = {0,0,0,0}, acc2 = {0,0,0,0}, acc3 = {0,0,0,0};
  const float4* __restrict__ Wv = (const float4*)Wc;   // [256][32]

  for (int k0 = 0; k0 < 256; k0 += 4){
    const float4 a0 = *(const float4*)&aT[n_t * 4 + 0][k0];
    const float4 a1 = *(const float4*)&aT[n_t * 4 + 1][k0];
    const float4 a2 = *(const float4*)&aT[n_t * 4 + 2][k0];
    const float4 a3 = *(const float4*)&aT[n_t * 4 + 3][k0];
    const float4 w0 = Wv[(size_t)(k0 + 0) * 32 + c_t];
    const float4 w1 = Wv[(size_t)(k0 + 1) * 32 + c_t];
    const float4 w2 = Wv[(size_t)(k0 + 2) * 32 + c_t];
    const float4 w3 = Wv[(size_t)(k0 + 3) * 32 + c_t];
    fma4(acc0, a0.x, w0); fma4(acc0, a0.y, w1); fma4(acc0, a0.z, w2); fma4(acc0, a0.w, w3);
    fma4(acc1, a1.x, w0); fma4(acc1, a1.y, w1); fma4(acc1, a1.z, w2); fma4(acc1, a1.w, w3);
    fma4(acc2, a2.x, w0); fma4(acc2, a2.y, w1); fma4(acc2, a2.z, w2); fma4(acc2, a2.w, w3);
    fma4(acc3, a3.x, w0); fma4(acc3, a3.y, w1); fma4(acc3, a3.z, w2); fma4(acc3, a3.w, w3);
  }

  const float alpha = *alpha_p;
  const float4 b4 = *(const float4*)&bias[c_t * 4];
  float4 accs[4] = {acc0, acc1, acc2, acc3};
  #pragma unroll
  for (int nn = 0; nn < 4; ++nn){
    int node = nb + n_t * 4 + nn;
    if (node < n){
      float4 v = accs[nn];
      v.x += b4.x; v.y += b4.y; v.z += b4.z; v.w += b4.w;
      v.x = fmaxf(v.x, 0.f) + alpha * fminf(v.x, 0.f);
      v.y = fmaxf(v.y, 0.f) + alpha * fminf(v.y, 0.f);
      v.z = fmaxf(v.z, 0.f) + alpha * fminf(v.z, 0.f);
      v.w = fmaxf(v.w, 0.f) + alpha * fminf(v.w, 0.f);
      *(float4*)&out[(size_t)node * 128 + c_t * 4] = v;
    }
  }
}

// ---------------- layer-3 fusion ----------------
// u[0..127]=wp@w3l, u[128..255]=wp@w3r, u[256]=wp.b3+bp
__global__ void k_u(const float* __restrict__ w3l, const float* __restrict__ w3r,
                    const float* __restrict__ b3, const float* __restrict__ wp,
                    const float* __restrict__ bp, float* __restrict__ u){
  int k = threadIdx.x;   // 128 threads
  float sl = 0.f, sr = 0.f;
  for (int o = 0; o < 64; ++o){
    float w = wp[o];
    sl = fmaf(w, w3l[o * 128 + k], sl);
    sr = fmaf(w, w3r[o * 128 + k], sr);
  }
  u[k] = sl; u[128 + k] = sr;
  if (k == 0){
    float c = bp[0];
    for (int o = 0; o < 64; ++o) c = fmaf(wp[o], b3[o], c);
    u[256] = c;
  }
}

// per node: s = h.u_l ; partial = h.u_r + c  (one wave per node)
__global__ __launch_bounds__(256) void k_dot(const float* __restrict__ h,
                                             const float* __restrict__ u,
                                             float* __restrict__ s,
                                             float* __restrict__ partial, int n){
  const int lane = threadIdx.x & 63;
  const int i = blockIdx.x * 4 + (threadIdx.x >> 6);
  if (i >= n) return;
  const float2 hv  = *(const float2*)&h[(size_t)i * 128 + lane * 2];
  const float2 ulv = *(const float2*)&u[lane * 2];
  const float2 urv = *(const float2*)&u[128 + lane * 2];
  float sv = hv.x * ulv.x + hv.y * ulv.y;
  float tv = hv.x * urv.x + hv.y * urv.y;
  #pragma unroll
  for (int off = 32; off > 0; off >>= 1){
    sv += __shfl_down(sv, off);
    tv += __shfl_down(tv, off);
  }
  if (lane == 0){ s[i] = sv; partial[i] = tv + u[256]; }
}

__global__ void k_final(const float* __restrict__ s, const float* __restrict__ partial,
                        const int* __restrict__ csr, const int* __restrict__ row_ptr,
                        const float* __restrict__ inv_cnt, float* __restrict__ out, int n){
  int i = blockIdx.x * blockDim.x + threadIdx.x;
  if (i >= n) return;
  int b = row_ptr[i], e = row_ptr[i + 1];
  float acc = 0.f;
  for (int j = b; j < e; ++j) acc += s[csr[j]];
  out[i] = acc * inv_cnt[i] + partial[i];
}

// ---------------- launch ----------------
extern "C" void kernel_launch(void* const* d_in, const int* in_sizes, int n_in,
                              void* d_out, int out_size, void* d_ws, size_t ws_size,
                              hipStream_t stream){
  const float* x   = (const float*)d_in[0];
  const int*   ei  = (const int*)d_in[1];
  const float* w1l = (const float*)d_in[2];
  const float* w1r = (const float*)d_in[3];
  const float* b1  = (const float*)d_in[4];
  const float* w2l = (const float*)d_in[5];
  const float* w2r = (const float*)d_in[6];
  const float* b2  = (const float*)d_in[7];
  const float* w3l = (const float*)d_in[8];
  const float* w3r = (const float*)d_in[9];
  const float* b3  = (const float*)d_in[10];
  const float* ap  = (const float*)d_in[11];
  const float* wp  = (const float*)d_in[12];
  const float* bp  = (const float*)d_in[13];

  const int n = out_size;              // 50000 nodes
  const int E = in_sizes[1] / 2;       // 800000 edges
  const int* srcI = ei;
  const int* dstI = ei + E;

  char* base = (char*)d_ws;
  size_t off = 0;
  auto take = [&](size_t bytes) -> char* {
    off = (off + 255) & ~(size_t)255;
    char* p = base + off;
    off += bytes;
    return p;
  };
  int*   cnt  = (int*)  take((size_t)n * 4);
  int*   rowp = (int*)  take(((size_t)n + 1) * 4);
  int*   fill = (int*)  take((size_t)n * 4);
  float* inv  = (float*)take((size_t)n * 4);
  int*   csr  = (int*)  take((size_t)E * 4);
  float* B1   = (float*)take((size_t)n * 128 * 4);   // agg buffer
  float* B2   = (float*)take((size_t)n * 128 * 4);   // h buffer
  float* sbuf = (float*)take((size_t)n * 4);
  float* pbuf = (float*)take((size_t)n * 4);
  float* u    = (float*)take(257 * 4);
  float* Wc   = (float*)take((size_t)256 * 128 * 4);
  (void)ws_size; (void)n_in;

  hipMemsetAsync(cnt, 0, (size_t)n * 4, stream);
  k_hist<<<1024, 256, 0, stream>>>(dstI, E, cnt);
  k_scan<<<1, 1024, 0, stream>>>(cnt, n, rowp, fill, inv);
  k_fill<<<1024, 256, 0, stream>>>(srcI, dstI, E, fill, csr);

  const int aggGrid  = (n * 64 + 255) / 256;
  const int gemmGrid = (n + 31) / 32;

  // layer 1: h1 = prelu([agg(x)|x] @ Wc1 + b1)
  k_agg <<<aggGrid, 256, 0, stream>>>(x, csr, rowp, inv, B1, n);
  k_wc  <<<128, 256, 0, stream>>>(w1l, w1r, Wc);
  k_gemm<<<gemmGrid, 256, 0, stream>>>(B1, x, Wc, b1, ap, B2, n);

  // layer 2: h2 = prelu([agg(h1)|h1] @ Wc2 + b2)  (in-place over h1)
  k_agg <<<aggGrid, 256, 0, stream>>>(B2, csr, rowp, inv, B1, n);
  k_wc  <<<128, 256, 0, stream>>>(w2l, w2r, Wc);
  k_gemm<<<gemmGrid, 256, 0, stream>>>(B1, B2, Wc, b2, ap, B2, n);

  // layer 3 + head, fused via u_l = wp@w3l, u_r = wp@w3r
  k_u    <<<1, 128, 0, stream>>>(w3l, w3r, b3, wp, bp, u);
  k_dot  <<<(n + 3) / 4, 256, 0, stream>>>(B2, u, sbuf, pbuf, n);
  k_final<<<(n + 255) / 256, 256, 0, stream>>>(sbuf, pbuf, csr, rowp, inv, (float*)d_out, n);
}

// Round 2
// 421.756 us; speedup vs baseline: 1.1430x; 1.1430x over previous
//
#include <hip/hip_runtime.h>
#include <cstdint>
#include <cstddef>

// ---------------- helpers ----------------
__device__ __forceinline__ void fma4(float4& acc, float s, const float4& w){
  acc.x = fmaf(s, w.x, acc.x);
  acc.y = fmaf(s, w.y, acc.y);
  acc.z = fmaf(s, w.z, acc.z);
  acc.w = fmaf(s, w.w, acc.w);
}

// ---------------- CSR build ----------------
__global__ void k_hist(const int* __restrict__ dst, int E, int* __restrict__ cnt){
  int i = blockIdx.x * blockDim.x + threadIdx.x;
  int stride = gridDim.x * blockDim.x;
  for (; i < E; i += stride) atomicAdd(&cnt[dst[i]], 1);
}

__global__ __launch_bounds__(1024) void k_scan(const int* __restrict__ cnt, int n,
                                               int* __restrict__ row_ptr,
                                               int* __restrict__ fill,
                                               float* __restrict__ inv_cnt){
  __shared__ int wsum[16];
  __shared__ int carry_s;
  const int t = threadIdx.x;
  const int lane = t & 63;
  const int wv = t >> 6;
  if (t == 0) carry_s = 0;
  __syncthreads();
  for (int base = 0; base < n; base += 1024){
    int i = base + t;
    int v = (i < n) ? cnt[i] : 0;
    int x = v;
    #pragma unroll
    for (int off = 1; off < 64; off <<= 1){
      int y = __shfl_up(x, off);
      if (lane >= off) x += y;
    }
    if (lane == 63) wsum[wv] = x;
    __syncthreads();
    if (wv == 0 && lane < 16){
      int s = wsum[lane];
      #pragma unroll
      for (int off = 1; off < 16; off <<= 1){
        int y = __shfl_up(s, off);
        if (lane >= off) s += y;
      }
      wsum[lane] = s;
    }
    __syncthreads();
    int waveoff = (wv == 0) ? 0 : wsum[wv - 1];
    int carry = carry_s;
    int incl = carry + waveoff + x;
    if (i < n){
      int excl = incl - v;
      row_ptr[i] = excl;
      fill[i] = excl;
      inv_cnt[i] = 1.0f / (float)((v > 0) ? v : 1);
    }
    __syncthreads();
    if (t == 1023) carry_s = incl;
    __syncthreads();
  }
  if (t == 0) row_ptr[n] = carry_s;
}

__global__ void k_fill(const int* __restrict__ src, const int* __restrict__ dst, int E,
                       int* __restrict__ fill, int* __restrict__ csr){
  int i = blockIdx.x * blockDim.x + threadIdx.x;
  int stride = gridDim.x * blockDim.x;
  for (; i < E; i += stride){
    int d = dst[i];
    int pos = atomicAdd(&fill[d], 1);
    csr[pos] = src[i];
  }
}

// ---------------- mean aggregation (gather) ----------------
// one wave per node, float2 per lane (128 floats/row), unroll-8 for MLP
__global__ __launch_bounds__(256) void k_agg(const float* __restrict__ feat,
                                             const int* __restrict__ csr,
                                             const int* __restrict__ row_ptr,
                                             const float* __restrict__ inv_cnt,
                                             float* __restrict__ outb, int n){
  const int lane = threadIdx.x & 63;
  const int node = (blockIdx.x * blockDim.x + threadIdx.x) >> 6;
  if (node >= n) return;
  const int beg = row_ptr[node];
  const int end = row_ptr[node + 1];
  const int lo = lane * 2;

  float ax0=0.f, ay0=0.f, ax1=0.f, ay1=0.f, ax2=0.f, ay2=0.f, ax3=0.f, ay3=0.f;
  float ax4=0.f, ay4=0.f, ax5=0.f, ay5=0.f, ax6=0.f, ay6=0.f, ax7=0.f, ay7=0.f;

  int j = beg;
  for (; j + 8 <= end; j += 8){
    const int s0 = csr[j+0], s1 = csr[j+1], s2 = csr[j+2], s3 = csr[j+3];
    const int s4 = csr[j+4], s5 = csr[j+5], s6 = csr[j+6], s7 = csr[j+7];
    const float2 v0 = *(const float2*)&feat[(size_t)s0 * 128 + lo];
    const float2 v1 = *(const float2*)&feat[(size_t)s1 * 128 + lo];
    const float2 v2 = *(const float2*)&feat[(size_t)s2 * 128 + lo];
    const float2 v3 = *(const float2*)&feat[(size_t)s3 * 128 + lo];
    const float2 v4 = *(const float2*)&feat[(size_t)s4 * 128 + lo];
    const float2 v5 = *(const float2*)&feat[(size_t)s5 * 128 + lo];
    const float2 v6 = *(const float2*)&feat[(size_t)s6 * 128 + lo];
    const float2 v7 = *(const float2*)&feat[(size_t)s7 * 128 + lo];
    ax0 += v0.x; ay0 += v0.y;  ax1 += v1.x; ay1 += v1.y;
    ax2 += v2.x; ay2 += v2.y;  ax3 += v3.x; ay3 += v3.y;
    ax4 += v4.x; ay4 += v4.y;  ax5 += v5.x; ay5 += v5.y;
    ax6 += v6.x; ay6 += v6.y;  ax7 += v7.x; ay7 += v7.y;
  }
  // 4-wide tail
  if (j + 4 <= end){
    const int s0 = csr[j+0], s1 = csr[j+1], s2 = csr[j+2], s3 = csr[j+3];
    const float2 v0 = *(const float2*)&feat[(size_t)s0 * 128 + lo];
    const float2 v1 = *(const float2*)&feat[(size_t)s1 * 128 + lo];
    const float2 v2 = *(const float2*)&feat[(size_t)s2 * 128 + lo];
    const float2 v3 = *(const float2*)&feat[(size_t)s3 * 128 + lo];
    ax0 += v0.x; ay0 += v0.y;  ax1 += v1.x; ay1 += v1.y;
    ax2 += v2.x; ay2 += v2.y;  ax3 += v3.x; ay3 += v3.y;
    j += 4;
  }
  // scalar tail (<=3)
  for (; j < end; ++j){
    const int s = csr[j];
    const float2 v = *(const float2*)&feat[(size_t)s * 128 + lo];
    ax4 += v.x; ay4 += v.y;
  }

  const float ic = inv_cnt[node];
  float2 o;
  o.x = (((ax0 + ax1) + (ax2 + ax3)) + ((ax4 + ax5) + (ax6 + ax7))) * ic;
  o.y = (((ay0 + ay1) + (ay2 + ay3)) + ((ay4 + ay5) + (ay6 + ay7))) * ic;
  *(float2*)&outb[(size_t)node * 128 + lo] = o;
}

// ---------------- weight pack: Wc[k][c], k-major ----------------
__global__ void k_wc(const float* __restrict__ wl, const float* __restrict__ wr,
                     float* __restrict__ wc){
  int id = blockIdx.x * 256 + threadIdx.x;
  if (id >= 256 * 128) return;
  int k = id >> 7, c = id & 127;
  wc[id] = (k < 128) ? wl[c * 128 + k] : wr[c * 128 + (k - 128)];
}

// ---------------- fused GEMM: out = prelu([A0|A1] @ Wc + b) ----------------
// 32-node tile/block, 256 threads, 4 nodes x 4 cols per thread
__global__ __launch_bounds__(256) void k_gemm(const float* __restrict__ A0,   // [n][128] -> k 0..127
                                              const float* __restrict__ A1,   // [n][128] -> k 128..255
                                              const float* __restrict__ Wc,   // [256][128]
                                              const float* __restrict__ bias, // [128]
                                              const float* __restrict__ alpha_p,
                                              float* __restrict__ out,        // [n][128]
                                              int n){
  __shared__ float aT[32][264];   // [node][k], pad 264 (1056B rows, 16B aligned)
  const int t = threadIdx.x;
  const int nb = blockIdx.x * 32;
  const int tcol = t & 31;   // k-quad
  const int trow = t >> 5;   // 0..7

  #pragma unroll
  for (int half = 0; half < 2; ++half){
    const float* __restrict__ src = half ? A1 : A0;
    #pragma unroll
    for (int rr = 0; rr < 4; ++rr){
      int r = rr * 8 + trow;
      int node = nb + r; if (node > n - 1) node = n - 1;
      const float4 v = *(const float4*)&src[(size_t)node * 128 + tcol * 4];
      *(float4*)&aT[r][half * 128 + tcol * 4] = v;
    }
  }
  __syncthreads();

  const int c_t = t & 31;   // col quad: cols c_t*4..+3
  const int n_t = t >> 5;   // node quad: nodes n_t*4..+3
  float4 acc0 = {0,0,0,0}, acc1 = {0,0,0,0}, acc2 = {0,0,0,0}, acc3 = {0,0,0,0};
  const float4* __restrict__ Wv = (const float4*)Wc;   // [256][32]

  for (int k0 = 0; k0 < 256; k0 += 4){
    const float4 a0 = *(const float4*)&aT[n_t * 4 + 0][k0];
    const float4 a1 = *(const float4*)&aT[n_t * 4 + 1][k0];
    const float4 a2 = *(const float4*)&aT[n_t * 4 + 2][k0];
    const float4 a3 = *(const float4*)&aT[n_t * 4 + 3][k0];
    const float4 w0 = Wv[(size_t)(k0 + 0) * 32 + c_t];
    const float4 w1 = Wv[(size_t)(k0 + 1) * 32 + c_t];
    const float4 w2 = Wv[(size_t)(k0 + 2) * 32 + c_t];
    const float4 w3 = Wv[(size_t)(k0 + 3) * 32 + c_t];
    fma4(acc0, a0.x, w0); fma4(acc0, a0.y, w1); fma4(acc0, a0.z, w2); fma4(acc0, a0.w, w3);
    fma4(acc1, a1.x, w0); fma4(acc1, a1.y, w1); fma4(acc1, a1.z, w2); fma4(acc1, a1.w, w3);
    fma4(acc2, a2.x, w0); fma4(acc2, a2.y, w1); fma4(acc2, a2.z, w2); fma4(acc2, a2.w, w3);
    fma4(acc3, a3.x, w0); fma4(acc3, a3.y, w1); fma4(acc3, a3.z, w2); fma4(acc3, a3.w, w3);
  }

  const float alpha = *alpha_p;
  const float4 b4 = *(const float4*)&bias[c_t * 4];
  float4 accs[4] = {acc0, acc1, acc2, acc3};
  #pragma unroll
  for (int nn = 0; nn < 4; ++nn){
    int node = nb + n_t * 4 + nn;
    if (node < n){
      float4 v = accs[nn];
      v.x += b4.x; v.y += b4.y; v.z += b4.z; v.w += b4.w;
      v.x = fmaxf(v.x, 0.f) + alpha * fminf(v.x, 0.f);
      v.y = fmaxf(v.y, 0.f) + alpha * fminf(v.y, 0.f);
      v.z = fmaxf(v.z, 0.f) + alpha * fminf(v.z, 0.f);
      v.w = fmaxf(v.w, 0.f) + alpha * fminf(v.w, 0.f);
      *(float4*)&out[(size_t)node * 128 + c_t * 4] = v;
    }
  }
}

// ---------------- layer-3 fusion ----------------
// u[0..127]=wp@w3l, u[128..255]=wp@w3r, u[256]=wp.b3+bp
__global__ void k_u(const float* __restrict__ w3l, const float* __restrict__ w3r,
                    const float* __restrict__ b3, const float* __restrict__ wp,
                    const float* __restrict__ bp, float* __restrict__ u){
  int k = threadIdx.x;   // 128 threads
  float sl = 0.f, sr = 0.f;
  for (int o = 0; o < 64; ++o){
    float w = wp[o];
    sl = fmaf(w, w3l[o * 128 + k], sl);
    sr = fmaf(w, w3r[o * 128 + k], sr);
  }
  u[k] = sl; u[128 + k] = sr;
  if (k == 0){
    float c = bp[0];
    for (int o = 0; o < 64; ++o) c = fmaf(wp[o], b3[o], c);
    u[256] = c;
  }
}

// per node: s = h.u_l ; partial = h.u_r + c  (one wave per node)
__global__ __launch_bounds__(256) void k_dot(const float* __restrict__ h,
                                             const float* __restrict__ u,
                                             float* __restrict__ s,
                                             float* __restrict__ partial, int n){
  const int lane = threadIdx.x & 63;
  const int i = blockIdx.x * 4 + (threadIdx.x >> 6);
  if (i >= n) return;
  const float2 hv  = *(const float2*)&h[(size_t)i * 128 + lane * 2];
  const float2 ulv = *(const float2*)&u[lane * 2];
  const float2 urv = *(const float2*)&u[128 + lane * 2];
  float sv = hv.x * ulv.x + hv.y * ulv.y;
  float tv = hv.x * urv.x + hv.y * urv.y;
  #pragma unroll
  for (int off = 32; off > 0; off >>= 1){
    sv += __shfl_down(sv, off);
    tv += __shfl_down(tv, off);
  }
  if (lane == 0){ s[i] = sv; partial[i] = tv + u[256]; }
}

// 4 lanes per node, stride-4 through neighbor list, 2-step shuffle reduce
__global__ __launch_bounds__(256) void k_final(const float* __restrict__ s, const float* __restrict__ partial,
                        const int* __restrict__ csr, const int* __restrict__ row_ptr,
                        const float* __restrict__ inv_cnt, float* __restrict__ out, int n){
  const int t = blockIdx.x * blockDim.x + threadIdx.x;
  const int node = t >> 2;
  const int sub = t & 3;
  if (node >= n) return;
  const int b = row_ptr[node], e = row_ptr[node + 1];
  float a0 = 0.f, a1 = 0.f;
  int j = b + sub;
  for (; j + 4 < e; j += 8){
    a0 += s[csr[j]];
    a1 += s[csr[j + 4]];
  }
  if (j < e) a0 += s[csr[j]];
  float acc = a0 + a1;
  acc += __shfl_down(acc, 1);
  acc += __shfl_down(acc, 2);
  if (sub == 0) out[node] = acc * inv_cnt[node] + partial[node];
}

// ---------------- launch ----------------
extern "C" void kernel_launch(void* const* d_in, const int* in_sizes, int n_in,
                              void* d_out, int out_size, void* d_ws, size_t ws_size,
                              hipStream_t stream){
  const float* x   = (const float*)d_in[0];
  const int*   ei  = (const int*)d_in[1];
  const float* w1l = (const float*)d_in[2];
  const float* w1r = (const float*)d_in[3];
  const float* b1  = (const float*)d_in[4];
  const float* w2l = (const float*)d_in[5];
  const float* w2r = (const float*)d_in[6];
  const float* b2  = (const float*)d_in[7];
  const float* w3l = (const float*)d_in[8];
  const float* w3r = (const float*)d_in[9];
  const float* b3  = (const float*)d_in[10];
  const float* ap  = (const float*)d_in[11];
  const float* wp  = (const float*)d_in[12];
  const float* bp  = (const float*)d_in[13];

  const int n = out_size;              // 50000 nodes
  const int E = in_sizes[1] / 2;       // 800000 edges
  const int* srcI = ei;
  const int* dstI = ei + E;

  char* base = (char*)d_ws;
  size_t off = 0;
  auto take = [&](size_t bytes) -> char* {
    off = (off + 255) & ~(size_t)255;
    char* p = base + off;
    off += bytes;
    return p;
  };
  int*   cnt  = (int*)  take((size_t)n * 4);
  int*   rowp = (int*)  take(((size_t)n + 1) * 4);
  int*   fill = (int*)  take((size_t)n * 4);
  float* inv  = (float*)take((size_t)n * 4);
  int*   csr  = (int*)  take((size_t)E * 4);
  float* B1   = (float*)take((size_t)n * 128 * 4);   // agg buffer
  float* B2   = (float*)take((size_t)n * 128 * 4);   // h buffer
  float* sbuf = (float*)take((size_t)n * 4);
  float* pbuf = (float*)take((size_t)n * 4);
  float* u    = (float*)take(257 * 4);
  float* Wc   = (float*)take((size_t)256 * 128 * 4);
  (void)ws_size; (void)n_in;

  hipMemsetAsync(cnt, 0, (size_t)n * 4, stream);
  k_hist<<<1024, 256, 0, stream>>>(dstI, E, cnt);
  k_scan<<<1, 1024, 0, stream>>>(cnt, n, rowp, fill, inv);
  k_fill<<<1024, 256, 0, stream>>>(srcI, dstI, E, fill, csr);

  const int aggGrid  = (n * 64 + 255) / 256;
  const int gemmGrid = (n + 31) / 32;

  // layer 1: h1 = prelu([agg(x)|x] @ Wc1 + b1)
  k_agg <<<aggGrid, 256, 0, stream>>>(x, csr, rowp, inv, B1, n);
  k_wc  <<<128, 256, 0, stream>>>(w1l, w1r, Wc);
  k_gemm<<<gemmGrid, 256, 0, stream>>>(B1, x, Wc, b1, ap, B2, n);

  // layer 2: h2 = prelu([agg(h1)|h1] @ Wc2 + b2)  (in-place over h1)
  k_agg <<<aggGrid, 256, 0, stream>>>(B2, csr, rowp, inv, B1, n);
  k_wc  <<<128, 256, 0, stream>>>(w2l, w2r, Wc);
  k_gemm<<<gemmGrid, 256, 0, stream>>>(B1, B2, Wc, b2, ap, B2, n);

  // layer 3 + head, fused via u_l = wp@w3l, u_r = wp@w3r
  k_u    <<<1, 128, 0, stream>>>(w3l, w3r, b3, wp, bp, u);
  k_dot  <<<(n + 3) / 4, 256, 0, stream>>>(B2, u, sbuf, pbuf, n);
  k_final<<<(n * 4 + 255) / 256, 256, 0, stream>>>(sbuf, pbuf, csr, rowp, inv, (float*)d_out, n);
}

// Round 5
// 421.244 us; speedup vs baseline: 1.1444x; 1.0012x over previous
//
#include <hip/hip_runtime.h>
#include <cstdint>
#include <cstddef>

typedef float f32x4 __attribute__((ext_vector_type(4)));
typedef short short8 __attribute__((ext_vector_type(8)));
typedef __bf16 bf16x8 __attribute__((ext_vector_type(8)));

// compiler-managed MFMA: hazards, wait-states, register classes handled by hipcc
__device__ __forceinline__ void mfma_bf16(f32x4& d, short8 a, short8 b){
  d = __builtin_amdgcn_mfma_f32_16x16x32_bf16(
        __builtin_bit_cast(bf16x8, a), __builtin_bit_cast(bf16x8, b), d, 0, 0, 0);
}

__device__ __forceinline__ unsigned short bf16_rn(float f){
  unsigned u = __float_as_uint(f);
  unsigned r = (u + 0x7FFF + ((u >> 16) & 1)) >> 16;
  return (unsigned short)r;
}

// ---------------- CSR build ----------------
__global__ void k_hist(const int* __restrict__ dst, int E, int* __restrict__ cnt){
  int i = blockIdx.x * blockDim.x + threadIdx.x;
  int stride = gridDim.x * blockDim.x;
  for (; i < E; i += stride) atomicAdd(&cnt[dst[i]], 1);
}

__global__ __launch_bounds__(1024) void k_scan(const int* __restrict__ cnt, int n,
                                               int* __restrict__ row_ptr,
                                               int* __restrict__ fill,
                                               float* __restrict__ inv_cnt){
  __shared__ int wsum[16];
  __shared__ int carry_s;
  const int t = threadIdx.x;
  const int lane = t & 63;
  const int wv = t >> 6;
  if (t == 0) carry_s = 0;
  __syncthreads();
  for (int base = 0; base < n; base += 1024){
    int i = base + t;
    int v = (i < n) ? cnt[i] : 0;
    int x = v;
    #pragma unroll
    for (int off = 1; off < 64; off <<= 1){
      int y = __shfl_up(x, off);
      if (lane >= off) x += y;
    }
    if (lane == 63) wsum[wv] = x;
    __syncthreads();
    if (wv == 0 && lane < 16){
      int s = wsum[lane];
      #pragma unroll
      for (int off = 1; off < 16; off <<= 1){
        int y = __shfl_up(s, off);
        if (lane >= off) s += y;
      }
      wsum[lane] = s;
    }
    __syncthreads();
    int waveoff = (wv == 0) ? 0 : wsum[wv - 1];
    int carry = carry_s;
    int incl = carry + waveoff + x;
    if (i < n){
      int excl = incl - v;
      row_ptr[i] = excl;
      fill[i] = excl;
      inv_cnt[i] = 1.0f / (float)((v > 0) ? v : 1);
    }
    __syncthreads();
    if (t == 1023) carry_s = incl;
    __syncthreads();
  }
  if (t == 0) row_ptr[n] = carry_s;
}

__global__ void k_fill(const int* __restrict__ src, const int* __restrict__ dst, int E,
                       int* __restrict__ fill, int* __restrict__ csr){
  int i = blockIdx.x * blockDim.x + threadIdx.x;
  int stride = gridDim.x * blockDim.x;
  for (; i < E; i += stride){
    int d = dst[i];
    int pos = atomicAdd(&fill[d], 1);
    csr[pos] = src[i];
  }
}

// ---------------- mean aggregation (gather), unroll-8 ----------------
__global__ __launch_bounds__(256) void k_agg(const float* __restrict__ feat,
                                             const int* __restrict__ csr,
                                             const int* __restrict__ row_ptr,
                                             const float* __restrict__ inv_cnt,
                                             float* __restrict__ outb, int n){
  const int lane = threadIdx.x & 63;
  const int node = (blockIdx.x * blockDim.x + threadIdx.x) >> 6;
  if (node >= n) return;
  const int beg = row_ptr[node];
  const int end = row_ptr[node + 1];
  const int lo = lane * 2;

  float ax0=0.f, ay0=0.f, ax1=0.f, ay1=0.f, ax2=0.f, ay2=0.f, ax3=0.f, ay3=0.f;
  float ax4=0.f, ay4=0.f, ax5=0.f, ay5=0.f, ax6=0.f, ay6=0.f, ax7=0.f, ay7=0.f;

  int j = beg;
  for (; j + 8 <= end; j += 8){
    const int s0 = csr[j+0], s1 = csr[j+1], s2 = csr[j+2], s3 = csr[j+3];
    const int s4 = csr[j+4], s5 = csr[j+5], s6 = csr[j+6], s7 = csr[j+7];
    const float2 v0 = *(const float2*)&feat[(size_t)s0 * 128 + lo];
    const float2 v1 = *(const float2*)&feat[(size_t)s1 * 128 + lo];
    const float2 v2 = *(const float2*)&feat[(size_t)s2 * 128 + lo];
    const float2 v3 = *(const float2*)&feat[(size_t)s3 * 128 + lo];
    const float2 v4 = *(const float2*)&feat[(size_t)s4 * 128 + lo];
    const float2 v5 = *(const float2*)&feat[(size_t)s5 * 128 + lo];
    const float2 v6 = *(const float2*)&feat[(size_t)s6 * 128 + lo];
    const float2 v7 = *(const float2*)&feat[(size_t)s7 * 128 + lo];
    ax0 += v0.x; ay0 += v0.y;  ax1 += v1.x; ay1 += v1.y;
    ax2 += v2.x; ay2 += v2.y;  ax3 += v3.x; ay3 += v3.y;
    ax4 += v4.x; ay4 += v4.y;  ax5 += v5.x; ay5 += v5.y;
    ax6 += v6.x; ay6 += v6.y;  ax7 += v7.x; ay7 += v7.y;
  }
  if (j + 4 <= end){
    const int s0 = csr[j+0], s1 = csr[j+1], s2 = csr[j+2], s3 = csr[j+3];
    const float2 v0 = *(const float2*)&feat[(size_t)s0 * 128 + lo];
    const float2 v1 = *(const float2*)&feat[(size_t)s1 * 128 + lo];
    const float2 v2 = *(const float2*)&feat[(size_t)s2 * 128 + lo];
    const float2 v3 = *(const float2*)&feat[(size_t)s3 * 128 + lo];
    ax0 += v0.x; ay0 += v0.y;  ax1 += v1.x; ay1 += v1.y;
    ax2 += v2.x; ay2 += v2.y;  ax3 += v3.x; ay3 += v3.y;
    j += 4;
  }
  for (; j < end; ++j){
    const int s = csr[j];
    const float2 v = *(const float2*)&feat[(size_t)s * 128 + lo];
    ax4 += v.x; ay4 += v.y;
  }

  const float ic = inv_cnt[node];
  float2 o;
  o.x = (((ax0 + ax1) + (ax2 + ax3)) + ((ax4 + ax5) + (ax6 + ax7))) * ic;
  o.y = (((ay0 + ay1) + (ay2 + ay3)) + ((ay4 + ay5) + (ay6 + ay7))) * ic;
  *(float2*)&outb[(size_t)node * 128 + lo] = o;
}

// ---------------- weight pack + bf16 hi/lo split ----------------
// Bt[c][k] = concat(wl,wr)[k][c]; c-major [128][256]
__global__ void k_wcs(const float* __restrict__ wl, const float* __restrict__ wr,
                      short* __restrict__ bth, short* __restrict__ btl){
  int id = blockIdx.x * 256 + threadIdx.x;
  if (id >= 128 * 256) return;
  int c = id >> 8, k = id & 255;
  float w = (k < 128) ? wl[c * 128 + k] : wr[c * 128 + (k - 128)];
  unsigned short h = bf16_rn(w);
  float hf = __uint_as_float((unsigned)h << 16);
  unsigned short l = bf16_rn(w - hf);
  bth[id] = (short)h;
  btl[id] = (short)l;
}

// ---------------- MFMA GEMM: out = prelu([A0|A1] @ Bt^T + b) ----------------
// block = 4 waves, 64 nodes; wave = 16 nodes x 128 cols; K=256 in 8 steps of 32
// split-bf16: D = Ah*Bh + Al*Bh + Ah*Bl  (fp32-grade)
__global__ __launch_bounds__(256) void k_gemm_mfma(const float* __restrict__ A0,  // [n][128] k 0..127
                                                   const float* __restrict__ A1,  // [n][128] k 128..255
                                                   const short* __restrict__ bth, // [128][256]
                                                   const short* __restrict__ btl, // [128][256]
                                                   const float* __restrict__ bias,
                                                   const float* __restrict__ alpha_p,
                                                   float* __restrict__ out,       // [n][128]
                                                   int n){
  const int t = threadIdx.x;
  const int lane = t & 63;
  const int wv = t >> 6;
  const int nodeBase = blockIdx.x * 64 + wv * 16;
  const int mrow = lane & 15;
  const int kgrp = lane >> 4;      // 0..3

  int node = nodeBase + mrow;
  if (node > n - 1) node = n - 1;
  const size_t arow = (size_t)node * 128;

  f32x4 acc[8];
  #pragma unroll
  for (int i = 0; i < 8; ++i) acc[i] = (f32x4){0.f, 0.f, 0.f, 0.f};

  #pragma unroll
  for (int ks = 0; ks < 8; ++ks){
    const float* __restrict__ Asrc = (ks < 4) ? A0 : A1;
    const int kk = (ks & 3) * 32 + kgrp * 8;
    const float4 v0 = *(const float4*)&Asrc[arow + kk];
    const float4 v1 = *(const float4*)&Asrc[arow + kk + 4];
    const float av[8] = {v0.x, v0.y, v0.z, v0.w, v1.x, v1.y, v1.z, v1.w};
    short8 ah, al;
    #pragma unroll
    for (int i = 0; i < 8; ++i){
      unsigned short h = bf16_rn(av[i]);
      ah[i] = (short)h;
      float hf = __uint_as_float((unsigned)h << 16);
      al[i] = (short)bf16_rn(av[i] - hf);
    }
    const int kb = ks * 32 + kgrp * 8;
    #pragma unroll
    for (int nt = 0; nt < 8; ++nt){
      const int ncol = nt * 16 + mrow;
      const short8 bh = *(const short8*)&bth[(size_t)ncol * 256 + kb];
      const short8 bl = *(const short8*)&btl[(size_t)ncol * 256 + kb];
      mfma_bf16(acc[nt], ah, bh);
      mfma_bf16(acc[nt], al, bh);
      mfma_bf16(acc[nt], ah, bl);
    }
  }

  const float alpha = *alpha_p;
  #pragma unroll
  for (int nt = 0; nt < 8; ++nt){
    const int col = nt * 16 + mrow;
    const float bv = bias[col];
    #pragma unroll
    for (int j = 0; j < 4; ++j){
      const int onode = nodeBase + kgrp * 4 + j;
      if (onode < n){
        float v = acc[nt][j] + bv;
        v = fmaxf(v, 0.f) + alpha * fminf(v, 0.f);
        out[(size_t)onode * 128 + col] = v;
      }
    }
  }
}

// ---------------- layer-3 fusion ----------------
__global__ void k_u(const float* __restrict__ w3l, const float* __restrict__ w3r,
                    const float* __restrict__ b3, const float* __restrict__ wp,
                    const float* __restrict__ bp, float* __restrict__ u){
  int k = threadIdx.x;   // 128 threads
  float sl = 0.f, sr = 0.f;
  for (int o = 0; o < 64; ++o){
    float w = wp[o];
    sl = fmaf(w, w3l[o * 128 + k], sl);
    sr = fmaf(w, w3r[o * 128 + k], sr);
  }
  u[k] = sl; u[128 + k] = sr;
  if (k == 0){
    float c = bp[0];
    for (int o = 0; o < 64; ++o) c = fmaf(wp[o], b3[o], c);
    u[256] = c;
  }
}

__global__ __launch_bounds__(256) void k_dot(const float* __restrict__ h,
                                             const float* __restrict__ u,
                                             float* __restrict__ s,
                                             float* __restrict__ partial, int n){
  const int lane = threadIdx.x & 63;
  const int i = blockIdx.x * 4 + (threadIdx.x >> 6);
  if (i >= n) return;
  const float2 hv  = *(const float2*)&h[(size_t)i * 128 + lane * 2];
  const float2 ulv = *(const float2*)&u[lane * 2];
  const float2 urv = *(const float2*)&u[128 + lane * 2];
  float sv = hv.x * ulv.x + hv.y * ulv.y;
  float tv = hv.x * urv.x + hv.y * urv.y;
  #pragma unroll
  for (int off = 32; off > 0; off >>= 1){
    sv += __shfl_down(sv, off);
    tv += __shfl_down(tv, off);
  }
  if (lane == 0){ s[i] = sv; partial[i] = tv + u[256]; }
}

__global__ __launch_bounds__(256) void k_final(const float* __restrict__ s, const float* __restrict__ partial,
                        const int* __restrict__ csr, const int* __restrict__ row_ptr,
                        const float* __restrict__ inv_cnt, float* __restrict__ out, int n){
  const int t = blockIdx.x * blockDim.x + threadIdx.x;
  const int node = t >> 2;
  const int sub = t & 3;
  if (node >= n) return;
  const int b = row_ptr[node], e = row_ptr[node + 1];
  float a0 = 0.f, a1 = 0.f;
  int j = b + sub;
  for (; j + 4 < e; j += 8){
    a0 += s[csr[j]];
    a1 += s[csr[j + 4]];
  }
  if (j < e) a0 += s[csr[j]];
  float acc = a0 + a1;
  acc += __shfl_down(acc, 1);
  acc += __shfl_down(acc, 2);
  if (sub == 0) out[node] = acc * inv_cnt[node] + partial[node];
}

// ---------------- launch ----------------
extern "C" void kernel_launch(void* const* d_in, const int* in_sizes, int n_in,
                              void* d_out, int out_size, void* d_ws, size_t ws_size,
                              hipStream_t stream){
  const float* x   = (const float*)d_in[0];
  const int*   ei  = (const int*)d_in[1];
  const float* w1l = (const float*)d_in[2];
  const float* w1r = (const float*)d_in[3];
  const float* b1  = (const float*)d_in[4];
  const float* w2l = (const float*)d_in[5];
  const float* w2r = (const float*)d_in[6];
  const float* b2  = (const float*)d_in[7];
  const float* w3l = (const float*)d_in[8];
  const float* w3r = (const float*)d_in[9];
  const float* b3  = (const float*)d_in[10];
  const float* ap  = (const float*)d_in[11];
  const float* wp  = (const float*)d_in[12];
  const float* bp  = (const float*)d_in[13];

  const int n = out_size;              // 50000 nodes
  const int E = in_sizes[1] / 2;       // 800000 edges
  const int* srcI = ei;
  const int* dstI = ei + E;

  char* base = (char*)d_ws;
  size_t off = 0;
  auto take = [&](size_t bytes) -> char* {
    off = (off + 255) & ~(size_t)255;
    char* p = base + off;
    off += bytes;
    return p;
  };
  int*   cnt  = (int*)  take((size_t)n * 4);
  int*   rowp = (int*)  take(((size_t)n + 1) * 4);
  int*   fill = (int*)  take((size_t)n * 4);
  float* inv  = (float*)take((size_t)n * 4);
  int*   csr  = (int*)  take((size_t)E * 4);
  float* B1   = (float*)take((size_t)n * 128 * 4);   // agg buffer
  float* B2   = (float*)take((size_t)n * 128 * 4);   // h buffer
  float* sbuf = (float*)take((size_t)n * 4);
  float* pbuf = (float*)take((size_t)n * 4);
  float* u    = (float*)take(257 * 4);
  short* bth  = (short*)take((size_t)128 * 256 * 2);
  short* btl  = (short*)take((size_t)128 * 256 * 2);
  (void)ws_size; (void)n_in;

  hipMemsetAsync(cnt, 0, (size_t)n * 4, stream);
  k_hist<<<1024, 256, 0, stream>>>(dstI, E, cnt);
  k_scan<<<1, 1024, 0, stream>>>(cnt, n, rowp, fill, inv);
  k_fill<<<1024, 256, 0, stream>>>(srcI, dstI, E, fill, csr);

  const int aggGrid  = (n * 64 + 255) / 256;
  const int gemmGrid = (n + 63) / 64;

  // layer 1: h1 = prelu([agg(x)|x] @ W1 + b1)
  k_agg      <<<aggGrid, 256, 0, stream>>>(x, csr, rowp, inv, B1, n);
  k_wcs      <<<128, 256, 0, stream>>>(w1l, w1r, bth, btl);
  k_gemm_mfma<<<gemmGrid, 256, 0, stream>>>(B1, x, bth, btl, b1, ap, B2, n);

  // layer 2: h2 = prelu([agg(h1)|h1] @ W2 + b2)
  k_agg      <<<aggGrid, 256, 0, stream>>>(B2, csr, rowp, inv, B1, n);
  k_wcs      <<<128, 256, 0, stream>>>(w2l, w2r, bth, btl);
  k_gemm_mfma<<<gemmGrid, 256, 0, stream>>>(B1, B2, bth, btl, b2, ap, B2, n);

  // layer 3 + head, fused via u_l = wp@w3l, u_r = wp@w3r
  k_u    <<<1, 128, 0, stream>>>(w3l, w3r, b3, wp, bp, u);
  k_dot  <<<(n + 3) / 4, 256, 0, stream>>>(B2, u, sbuf, pbuf, n);
  k_final<<<(n * 4 + 255) / 256, 256, 0, stream>>>(sbuf, pbuf, csr, rowp, inv, (float*)d_out, n);
}

// Round 6
// 358.544 us; speedup vs baseline: 1.3445x; 1.1749x over previous
//
#include <hip/hip_runtime.h>
#include <cstdint>
#include <cstddef>

typedef float f32x4 __attribute__((ext_vector_type(4)));
typedef short short8 __attribute__((ext_vector_type(8)));
typedef __bf16 bf16x8 __attribute__((ext_vector_type(8)));

// compiler-managed MFMA: hazards, wait-states, register classes handled by hipcc
__device__ __forceinline__ void mfma_bf16(f32x4& d, short8 a, short8 b){
  d = __builtin_amdgcn_mfma_f32_16x16x32_bf16(
        __builtin_bit_cast(bf16x8, a), __builtin_bit_cast(bf16x8, b), d, 0, 0, 0);
}

__device__ __forceinline__ unsigned short bf16_rn(float f){
  unsigned u = __float_as_uint(f);
  unsigned r = (u + 0x7FFF + ((u >> 16) & 1)) >> 16;
  return (unsigned short)r;
}

// ---------------- CSR build ----------------
__global__ void k_hist(const int* __restrict__ dst, int E, int* __restrict__ cnt){
  int i = blockIdx.x * blockDim.x + threadIdx.x;
  int stride = gridDim.x * blockDim.x;
  for (; i < E; i += stride) atomicAdd(&cnt[dst[i]], 1);
}

__global__ __launch_bounds__(1024) void k_scan(const int* __restrict__ cnt, int n,
                                               int* __restrict__ row_ptr,
                                               int* __restrict__ fill,
                                               float* __restrict__ inv_cnt){
  __shared__ int wsum[16];
  __shared__ int carry_s;
  const int t = threadIdx.x;
  const int lane = t & 63;
  const int wv = t >> 6;
  if (t == 0) carry_s = 0;
  __syncthreads();
  for (int base = 0; base < n; base += 1024){
    int i = base + t;
    int v = (i < n) ? cnt[i] : 0;
    int x = v;
    #pragma unroll
    for (int off = 1; off < 64; off <<= 1){
      int y = __shfl_up(x, off);
      if (lane >= off) x += y;
    }
    if (lane == 63) wsum[wv] = x;
    __syncthreads();
    if (wv == 0 && lane < 16){
      int s = wsum[lane];
      #pragma unroll
      for (int off = 1; off < 16; off <<= 1){
        int y = __shfl_up(s, off);
        if (lane >= off) s += y;
      }
      wsum[lane] = s;
    }
    __syncthreads();
    int waveoff = (wv == 0) ? 0 : wsum[wv - 1];
    int carry = carry_s;
    int incl = carry + waveoff + x;
    if (i < n){
      int excl = incl - v;
      row_ptr[i] = excl;
      fill[i] = excl;
      inv_cnt[i] = 1.0f / (float)((v > 0) ? v : 1);
    }
    __syncthreads();
    if (t == 1023) carry_s = incl;
    __syncthreads();
  }
  if (t == 0) row_ptr[n] = carry_s;
}

__global__ void k_fill(const int* __restrict__ src, const int* __restrict__ dst, int E,
                       int* __restrict__ fill, int* __restrict__ csr){
  int i = blockIdx.x * blockDim.x + threadIdx.x;
  int stride = gridDim.x * blockDim.x;
  for (; i < E; i += stride){
    int d = dst[i];
    int pos = atomicAdd(&fill[d], 1);
    csr[pos] = src[i];
  }
}

// ---------------- mean aggregation (gather), unroll-8 ----------------
__global__ __launch_bounds__(256) void k_agg(const float* __restrict__ feat,
                                             const int* __restrict__ csr,
                                             const int* __restrict__ row_ptr,
                                             const float* __restrict__ inv_cnt,
                                             float* __restrict__ outb, int n){
  const int lane = threadIdx.x & 63;
  const int node = (blockIdx.x * blockDim.x + threadIdx.x) >> 6;
  if (node >= n) return;
  const int beg = row_ptr[node];
  const int end = row_ptr[node + 1];
  const int lo = lane * 2;

  float ax0=0.f, ay0=0.f, ax1=0.f, ay1=0.f, ax2=0.f, ay2=0.f, ax3=0.f, ay3=0.f;
  float ax4=0.f, ay4=0.f, ax5=0.f, ay5=0.f, ax6=0.f, ay6=0.f, ax7=0.f, ay7=0.f;

  int j = beg;
  for (; j + 8 <= end; j += 8){
    const int s0 = csr[j+0], s1 = csr[j+1], s2 = csr[j+2], s3 = csr[j+3];
    const int s4 = csr[j+4], s5 = csr[j+5], s6 = csr[j+6], s7 = csr[j+7];
    const float2 v0 = *(const float2*)&feat[(size_t)s0 * 128 + lo];
    const float2 v1 = *(const float2*)&feat[(size_t)s1 * 128 + lo];
    const float2 v2 = *(const float2*)&feat[(size_t)s2 * 128 + lo];
    const float2 v3 = *(const float2*)&feat[(size_t)s3 * 128 + lo];
    const float2 v4 = *(const float2*)&feat[(size_t)s4 * 128 + lo];
    const float2 v5 = *(const float2*)&feat[(size_t)s5 * 128 + lo];
    const float2 v6 = *(const float2*)&feat[(size_t)s6 * 128 + lo];
    const float2 v7 = *(const float2*)&feat[(size_t)s7 * 128 + lo];
    ax0 += v0.x; ay0 += v0.y;  ax1 += v1.x; ay1 += v1.y;
    ax2 += v2.x; ay2 += v2.y;  ax3 += v3.x; ay3 += v3.y;
    ax4 += v4.x; ay4 += v4.y;  ax5 += v5.x; ay5 += v5.y;
    ax6 += v6.x; ay6 += v6.y;  ax7 += v7.x; ay7 += v7.y;
  }
  if (j + 4 <= end){
    const int s0 = csr[j+0], s1 = csr[j+1], s2 = csr[j+2], s3 = csr[j+3];
    const float2 v0 = *(const float2*)&feat[(size_t)s0 * 128 + lo];
    const float2 v1 = *(const float2*)&feat[(size_t)s1 * 128 + lo];
    const float2 v2 = *(const float2*)&feat[(size_t)s2 * 128 + lo];
    const float2 v3 = *(const float2*)&feat[(size_t)s3 * 128 + lo];
    ax0 += v0.x; ay0 += v0.y;  ax1 += v1.x; ay1 += v1.y;
    ax2 += v2.x; ay2 += v2.y;  ax3 += v3.x; ay3 += v3.y;
    j += 4;
  }
  for (; j < end; ++j){
    const int s = csr[j];
    const float2 v = *(const float2*)&feat[(size_t)s * 128 + lo];
    ax4 += v.x; ay4 += v.y;
  }

  const float ic = inv_cnt[node];
  float2 o;
  o.x = (((ax0 + ax1) + (ax2 + ax3)) + ((ax4 + ax5) + (ax6 + ax7))) * ic;
  o.y = (((ay0 + ay1) + (ay2 + ay3)) + ((ay4 + ay5) + (ay6 + ay7))) * ic;
  *(float2*)&outb[(size_t)node * 128 + lo] = o;
}

// ---------------- weight pack + bf16 hi/lo split, FRAGMENT-MAJOR ----------------
// W[k][c] = concat(wl,wr) row-major over k.  Fragment f = (ks*8 + nt)*2 + hl,
// ks=k>>5 (K-step of 32), nt=c>>4 (col tile).  Within a fragment, lane = kgrp*16+mrow
// (kgrp=(k>>3)&3, mrow=c&15), element j = k&7.  Each fragment = 512 shorts = 1 KB,
// so a wave's B-load is one contiguous 64-lane x 16B burst.
__global__ void k_wcs(const float* __restrict__ wl, const float* __restrict__ wr,
                      short* __restrict__ bfr){
  int id = blockIdx.x * 256 + threadIdx.x;
  if (id >= 128 * 256) return;
  int c = id >> 8, k = id & 255;
  float w = (k < 128) ? wl[c * 128 + k] : wr[c * 128 + (k - 128)];
  unsigned short h = bf16_rn(w);
  float hf = __uint_as_float((unsigned)h << 16);
  unsigned short l = bf16_rn(w - hf);
  const int nt = c >> 4, mrow = c & 15;
  const int ks = k >> 5, kgrp = (k >> 3) & 3, j = k & 7;
  const int lane = kgrp * 16 + mrow;
  const size_t fbase = (size_t)((ks * 8 + nt) * 2) * 512 + lane * 8 + j;
  bfr[fbase] = (short)h;          // hi fragment
  bfr[fbase + 512] = (short)l;    // lo fragment (f+1)
}

// ---------------- MFMA GEMM: out = prelu([A0|A1] @ W^T + b) ----------------
// block = 4 waves, 64 nodes; wave = 16 nodes x 128 cols; K=256 in 8 steps of 32
// split-bf16: D = Ah*Bh + Al*Bh + Ah*Bl  (fp32-grade)
__global__ __launch_bounds__(256) void k_gemm_mfma(const float* __restrict__ A0,  // [n][128] k 0..127
                                                   const float* __restrict__ A1,  // [n][128] k 128..255
                                                   const short* __restrict__ bfr, // 128 frags x 512
                                                   const float* __restrict__ bias,
                                                   const float* __restrict__ alpha_p,
                                                   float* __restrict__ out,       // [n][128]
                                                   int n){
  const int t = threadIdx.x;
  const int lane = t & 63;
  const int wv = t >> 6;
  const int nodeBase = blockIdx.x * 64 + wv * 16;
  const int mrow = lane & 15;
  const int kgrp = lane >> 4;      // 0..3

  int node = nodeBase + mrow;
  if (node > n - 1) node = n - 1;
  const size_t arow = (size_t)node * 128;

  const short8* __restrict__ Bf = (const short8*)bfr;   // [frag][64 lanes]

  f32x4 acc[8];
  #pragma unroll
  for (int i = 0; i < 8; ++i) acc[i] = (f32x4){0.f, 0.f, 0.f, 0.f};

  #pragma unroll
  for (int ks = 0; ks < 8; ++ks){
    const float* __restrict__ Asrc = (ks < 4) ? A0 : A1;
    const int kk = (ks & 3) * 32 + kgrp * 8;
    const float4 v0 = *(const float4*)&Asrc[arow + kk];
    const float4 v1 = *(const float4*)&Asrc[arow + kk + 4];

    // batch-load all 16 B fragments of this k-step (coalesced 1KB bursts, L2-hot)
    short8 bh[8], bl[8];
    const int fb = ks * 16;   // (ks*8 + nt)*2
    #pragma unroll
    for (int nt = 0; nt < 8; ++nt){
      bh[nt] = Bf[(size_t)(fb + nt * 2 + 0) * 64 + lane];
      bl[nt] = Bf[(size_t)(fb + nt * 2 + 1) * 64 + lane];
    }

    const float av[8] = {v0.x, v0.y, v0.z, v0.w, v1.x, v1.y, v1.z, v1.w};
    short8 ah, al;
    #pragma unroll
    for (int i = 0; i < 8; ++i){
      unsigned short h = bf16_rn(av[i]);
      ah[i] = (short)h;
      float hf = __uint_as_float((unsigned)h << 16);
      al[i] = (short)bf16_rn(av[i] - hf);
    }

    #pragma unroll
    for (int nt = 0; nt < 8; ++nt){
      mfma_bf16(acc[nt], ah, bh[nt]);
      mfma_bf16(acc[nt], al, bh[nt]);
      mfma_bf16(acc[nt], ah, bl[nt]);
    }
  }

  const float alpha = *alpha_p;
  #pragma unroll
  for (int nt = 0; nt < 8; ++nt){
    const int col = nt * 16 + mrow;
    const float bv = bias[col];
    #pragma unroll
    for (int j = 0; j < 4; ++j){
      const int onode = nodeBase + kgrp * 4 + j;
      if (onode < n){
        float v = acc[nt][j] + bv;
        v = fmaxf(v, 0.f) + alpha * fminf(v, 0.f);
        out[(size_t)onode * 128 + col] = v;
      }
    }
  }
}

// ---------------- layer-3 fusion ----------------
__global__ void k_u(const float* __restrict__ w3l, const float* __restrict__ w3r,
                    const float* __restrict__ b3, const float* __restrict__ wp,
                    const float* __restrict__ bp, float* __restrict__ u){
  int k = threadIdx.x;   // 128 threads
  float sl = 0.f, sr = 0.f;
  for (int o = 0; o < 64; ++o){
    float w = wp[o];
    sl = fmaf(w, w3l[o * 128 + k], sl);
    sr = fmaf(w, w3r[o * 128 + k], sr);
  }
  u[k] = sl; u[128 + k] = sr;
  if (k == 0){
    float c = bp[0];
    for (int o = 0; o < 64; ++o) c = fmaf(wp[o], b3[o], c);
    u[256] = c;
  }
}

__global__ __launch_bounds__(256) void k_dot(const float* __restrict__ h,
                                             const float* __restrict__ u,
                                             float* __restrict__ s,
                                             float* __restrict__ partial, int n){
  const int lane = threadIdx.x & 63;
  const int i = blockIdx.x * 4 + (threadIdx.x >> 6);
  if (i >= n) return;
  const float2 hv  = *(const float2*)&h[(size_t)i * 128 + lane * 2];
  const float2 ulv = *(const float2*)&u[lane * 2];
  const float2 urv = *(const float2*)&u[128 + lane * 2];
  float sv = hv.x * ulv.x + hv.y * ulv.y;
  float tv = hv.x * urv.x + hv.y * urv.y;
  #pragma unroll
  for (int off = 32; off > 0; off >>= 1){
    sv += __shfl_down(sv, off);
    tv += __shfl_down(tv, off);
  }
  if (lane == 0){ s[i] = sv; partial[i] = tv + u[256]; }
}

__global__ __launch_bounds__(256) void k_final(const float* __restrict__ s, const float* __restrict__ partial,
                        const int* __restrict__ csr, const int* __restrict__ row_ptr,
                        const float* __restrict__ inv_cnt, float* __restrict__ out, int n){
  const int t = blockIdx.x * blockDim.x + threadIdx.x;
  const int node = t >> 2;
  const int sub = t & 3;
  if (node >= n) return;
  const int b = row_ptr[node], e = row_ptr[node + 1];
  float a0 = 0.f, a1 = 0.f;
  int j = b + sub;
  for (; j + 4 < e; j += 8){
    a0 += s[csr[j]];
    a1 += s[csr[j + 4]];
  }
  if (j < e) a0 += s[csr[j]];
  float acc = a0 + a1;
  acc += __shfl_down(acc, 1);
  acc += __shfl_down(acc, 2);
  if (sub == 0) out[node] = acc * inv_cnt[node] + partial[node];
}

// ---------------- launch ----------------
extern "C" void kernel_launch(void* const* d_in, const int* in_sizes, int n_in,
                              void* d_out, int out_size, void* d_ws, size_t ws_size,
                              hipStream_t stream){
  const float* x   = (const float*)d_in[0];
  const int*   ei  = (const int*)d_in[1];
  const float* w1l = (const float*)d_in[2];
  const float* w1r = (const float*)d_in[3];
  const float* b1  = (const float*)d_in[4];
  const float* w2l = (const float*)d_in[5];
  const float* w2r = (const float*)d_in[6];
  const float* b2  = (const float*)d_in[7];
  const float* w3l = (const float*)d_in[8];
  const float* w3r = (const float*)d_in[9];
  const float* b3  = (const float*)d_in[10];
  const float* ap  = (const float*)d_in[11];
  const float* wp  = (const float*)d_in[12];
  const float* bp  = (const float*)d_in[13];

  const int n = out_size;              // 50000 nodes
  const int E = in_sizes[1] / 2;       // 800000 edges
  const int* srcI = ei;
  const int* dstI = ei + E;

  char* base = (char*)d_ws;
  size_t off = 0;
  auto take = [&](size_t bytes) -> char* {
    off = (off + 255) & ~(size_t)255;
    char* p = base + off;
    off += bytes;
    return p;
  };
  int*   cnt  = (int*)  take((size_t)n * 4);
  int*   rowp = (int*)  take(((size_t)n + 1) * 4);
  int*   fill = (int*)  take((size_t)n * 4);
  float* inv  = (float*)take((size_t)n * 4);
  int*   csr  = (int*)  take((size_t)E * 4);
  float* B1   = (float*)take((size_t)n * 128 * 4);   // agg buffer
  float* B2   = (float*)take((size_t)n * 128 * 4);   // h buffer
  float* sbuf = (float*)take((size_t)n * 4);
  float* pbuf = (float*)take((size_t)n * 4);
  float* u    = (float*)take(257 * 4);
  short* bfr  = (short*)take((size_t)128 * 512 * 2); // 128 frags x 512 shorts
  (void)ws_size; (void)n_in;

  hipMemsetAsync(cnt, 0, (size_t)n * 4, stream);
  k_hist<<<1024, 256, 0, stream>>>(dstI, E, cnt);
  k_scan<<<1, 1024, 0, stream>>>(cnt, n, rowp, fill, inv);
  k_fill<<<1024, 256, 0, stream>>>(srcI, dstI, E, fill, csr);

  const int aggGrid  = (n * 64 + 255) / 256;
  const int gemmGrid = (n + 63) / 64;

  // layer 1: h1 = prelu([agg(x)|x] @ W1 + b1)
  k_agg      <<<aggGrid, 256, 0, stream>>>(x, csr, rowp, inv, B1, n);
  k_wcs      <<<128, 256, 0, stream>>>(w1l, w1r, bfr);
  k_gemm_mfma<<<gemmGrid, 256, 0, stream>>>(B1, x, bfr, b1, ap, B2, n);

  // layer 2: h2 = prelu([agg(h1)|h1] @ W2 + b2)
  k_agg      <<<aggGrid, 256, 0, stream>>>(B2, csr, rowp, inv, B1, n);
  k_wcs      <<<128, 256, 0, stream>>>(w2l, w2r, bfr);
  k_gemm_mfma<<<gemmGrid, 256, 0, stream>>>(B1, B2, bfr, b2, ap, B2, n);

  // layer 3 + head, fused via u_l = wp@w3l, u_r = wp@w3r
  k_u    <<<1, 128, 0, stream>>>(w3l, w3r, b3, wp, bp, u);
  k_dot  <<<(n + 3) / 4, 256, 0, stream>>>(B2, u, sbuf, pbuf, n);
  k_final<<<(n * 4 + 255) / 256, 256, 0, stream>>>(sbuf, pbuf, csr, rowp, inv, (float*)d_out, n);
}

// Round 7
// 224.410 us; speedup vs baseline: 2.1481x; 1.5977x over previous
//
#include <hip/hip_runtime.h>
#include <cstdint>
#include <cstddef>

typedef float f32x4 __attribute__((ext_vector_type(4)));
typedef short short8 __attribute__((ext_vector_type(8)));
typedef __bf16 bf16x8 __attribute__((ext_vector_type(8)));

__device__ __forceinline__ void mfma_bf16(f32x4& d, short8 a, short8 b){
  d = __builtin_amdgcn_mfma_f32_16x16x32_bf16(
        __builtin_bit_cast(bf16x8, a), __builtin_bit_cast(bf16x8, b), d, 0, 0, 0);
}

__device__ __forceinline__ unsigned short bf16_rn(float f){
  unsigned u = __float_as_uint(f);
  unsigned r = (u + 0x7FFF + ((u >> 16) & 1)) >> 16;
  return (unsigned short)r;
}

// 256-thread exclusive block scan (4 waves). Caller must __syncthreads()
// before touching wsum again / after using results that feed LDS.
__device__ __forceinline__ int blockScan256Excl(int v, int* wsum){
  const int lane = threadIdx.x & 63, wv = threadIdx.x >> 6;
  int x = v;
  #pragma unroll
  for (int off = 1; off < 64; off <<= 1){
    int y = __shfl_up(x, off);
    if (lane >= off) x += y;
  }
  if (lane == 63) wsum[wv] = x;
  __syncthreads();
  int woff = 0;
  #pragma unroll
  for (int w = 0; w < 4; ++w) woff += (w < wv) ? wsum[w] : 0;
  return woff + x - v;
}

// ================= CSR build: two-level counting sort (no global atomics) =================
// bucket(d) = d >> 8 ; nb = ceil(n/256) <= 256 ; tile = 2048 edges

__global__ __launch_bounds__(256) void k_bcount(const int* __restrict__ dst, int E, int nb, int ntiles,
                                                int* __restrict__ blk_hist /*[bucket][tile]*/){
  __shared__ int h[256];
  const int tile = blockIdx.x;
  h[threadIdx.x] = 0;
  __syncthreads();
  const int base = tile * 2048;
  const int end = min(base + 2048, E);
  for (int i = base + threadIdx.x; i < end; i += 256)
    atomicAdd(&h[dst[i] >> 8], 1);
  __syncthreads();
  const int b = threadIdx.x;
  if (b < nb) blk_hist[(size_t)b * ntiles + tile] = h[b];
}

__global__ __launch_bounds__(256) void k_bscan(int* __restrict__ blk_hist, int nb, int ntiles,
                                               int* __restrict__ tot){
  __shared__ int wsum[4];
  __shared__ int carry;
  const int b = blockIdx.x;
  int* row = blk_hist + (size_t)b * ntiles;
  if (threadIdx.x == 0) carry = 0;
  __syncthreads();
  const int lane = threadIdx.x & 63, wv = threadIdx.x >> 6;
  for (int base = 0; base < ntiles; base += 256){
    const int i = base + threadIdx.x;
    const int v = (i < ntiles) ? row[i] : 0;
    int x = v;
    #pragma unroll
    for (int off = 1; off < 64; off <<= 1){
      int y = __shfl_up(x, off);
      if (lane >= off) x += y;
    }
    if (lane == 63) wsum[wv] = x;
    __syncthreads();
    int woff = 0;
    #pragma unroll
    for (int w = 0; w < 4; ++w) woff += (w < wv) ? wsum[w] : 0;
    const int incl = carry + woff + x;
    if (i < ntiles) row[i] = incl - v;   // exclusive offset within bucket
    __syncthreads();
    if (threadIdx.x == 255) carry = incl;
    __syncthreads();
  }
  if (threadIdx.x == 0) tot[b] = carry;
}

__global__ __launch_bounds__(256) void k_btot(const int* __restrict__ tot, int nb,
                                              int* __restrict__ bucket_base){
  __shared__ int wsum[4];
  const int t = threadIdx.x;
  const int v = (t < nb) ? tot[t] : 0;
  const int e = blockScan256Excl(v, wsum);
  if (t <= nb) bucket_base[t] = e;   // t==nb gets total (=E)
}

__global__ __launch_bounds__(256) void k_bscat(const int* __restrict__ src, const int* __restrict__ dst,
                                               int E, int nb, int ntiles,
                                               const int* __restrict__ blk_off,      // [bucket][tile] excl
                                               const int* __restrict__ bucket_base,
                                               unsigned* __restrict__ ebuf){
  __shared__ int cnt[256];
  __shared__ int lofs[256];
  __shared__ int gbase[256];
  __shared__ unsigned sorted[2048];
  __shared__ unsigned char sb[2048];
  __shared__ int wsum[4];
  const int tile = blockIdx.x;
  cnt[threadIdx.x] = 0;
  __syncthreads();
  const int base = tile * 2048;
  const int end = min(base + 2048, E);
  const int m = end - base;

  int rank_[8]; int b_[8]; unsigned v_[8];
  #pragma unroll
  for (int k = 0; k < 8; ++k){
    const int j = threadIdx.x + k * 256;
    if (base + j < end){
      const int d = dst[base + j];
      const int s = src[base + j];
      const int b = d >> 8;
      b_[k] = b;
      v_[k] = ((unsigned)(d & 255) << 16) | (unsigned)s;
      rank_[k] = atomicAdd(&cnt[b], 1);
    } else b_[k] = -1;
  }
  __syncthreads();
  const int ex = blockScan256Excl(cnt[threadIdx.x], wsum);
  lofs[threadIdx.x] = ex;
  if (threadIdx.x < nb)
    gbase[threadIdx.x] = bucket_base[threadIdx.x] + blk_off[(size_t)threadIdx.x * ntiles + tile];
  __syncthreads();
  #pragma unroll
  for (int k = 0; k < 8; ++k){
    if (b_[k] >= 0){
      const int p = lofs[b_[k]] + rank_[k];
      sorted[p] = v_[k];
      sb[p] = (unsigned char)b_[k];
    }
  }
  __syncthreads();
  for (int j = threadIdx.x; j < m; j += 256){
    const int b = sb[j];
    ebuf[gbase[b] + (j - lofs[b])] = sorted[j];
  }
}

__global__ __launch_bounds__(256) void k_csrfin(const unsigned* __restrict__ ebuf,
                                                const int* __restrict__ bucket_base,
                                                int n, int E, int nb,
                                                int* __restrict__ row_ptr,
                                                float* __restrict__ inv,
                                                unsigned short* __restrict__ csr){
  __shared__ int hist[256], excl[256], cursor[256];
  __shared__ int wsum[4];
  __shared__ unsigned vals[8192];          // 2x headroom over mean 4096 edges/bucket
  __shared__ unsigned short sorted[8192];
  const int b = blockIdx.x;
  const int ebase = bucket_base[b];
  const int ecnt = bucket_base[b + 1] - ebase;
  const int t = threadIdx.x;
  hist[t] = 0;
  __syncthreads();
  for (int j = t; j < ecnt; j += 256){
    const unsigned v = ebuf[ebase + j];
    vals[j] = v;
    atomicAdd(&hist[v >> 16], 1);
  }
  __syncthreads();
  const int ex = blockScan256Excl(hist[t], wsum);
  excl[t] = ex;
  cursor[t] = ex;
  const int node = b * 256 + t;
  if (node < n){
    row_ptr[node] = ebase + ex;
    const int c = hist[t];
    inv[node] = 1.0f / (float)(c > 0 ? c : 1);
  }
  if (b == nb - 1 && t == 0) row_ptr[n] = E;
  __syncthreads();
  for (int j = t; j < ecnt; j += 256){
    const unsigned v = vals[j];
    const int pos = atomicAdd(&cursor[v >> 16], 1);
    sorted[pos] = (unsigned short)(v & 0xFFFFu);
  }
  __syncthreads();
  for (int j = t; j < ecnt; j += 256)
    csr[ebase + j] = sorted[j];
}

// ---------------- mean aggregation (gather), unroll-8, u16 csr ----------------
__global__ __launch_bounds__(256) void k_agg(const float* __restrict__ feat,
                                             const unsigned short* __restrict__ csr,
                                             const int* __restrict__ row_ptr,
                                             const float* __restrict__ inv_cnt,
                                             float* __restrict__ outb, int n){
  const int lane = threadIdx.x & 63;
  const int node = (blockIdx.x * blockDim.x + threadIdx.x) >> 6;
  if (node >= n) return;
  const int beg = row_ptr[node];
  const int end = row_ptr[node + 1];
  const int lo = lane * 2;

  float ax0=0.f, ay0=0.f, ax1=0.f, ay1=0.f, ax2=0.f, ay2=0.f, ax3=0.f, ay3=0.f;
  float ax4=0.f, ay4=0.f, ax5=0.f, ay5=0.f, ax6=0.f, ay6=0.f, ax7=0.f, ay7=0.f;

  int j = beg;
  for (; j + 8 <= end; j += 8){
    const int s0 = csr[j+0], s1 = csr[j+1], s2 = csr[j+2], s3 = csr[j+3];
    const int s4 = csr[j+4], s5 = csr[j+5], s6 = csr[j+6], s7 = csr[j+7];
    const float2 v0 = *(const float2*)&feat[(size_t)s0 * 128 + lo];
    const float2 v1 = *(const float2*)&feat[(size_t)s1 * 128 + lo];
    const float2 v2 = *(const float2*)&feat[(size_t)s2 * 128 + lo];
    const float2 v3 = *(const float2*)&feat[(size_t)s3 * 128 + lo];
    const float2 v4 = *(const float2*)&feat[(size_t)s4 * 128 + lo];
    const float2 v5 = *(const float2*)&feat[(size_t)s5 * 128 + lo];
    const float2 v6 = *(const float2*)&feat[(size_t)s6 * 128 + lo];
    const float2 v7 = *(const float2*)&feat[(size_t)s7 * 128 + lo];
    ax0 += v0.x; ay0 += v0.y;  ax1 += v1.x; ay1 += v1.y;
    ax2 += v2.x; ay2 += v2.y;  ax3 += v3.x; ay3 += v3.y;
    ax4 += v4.x; ay4 += v4.y;  ax5 += v5.x; ay5 += v5.y;
    ax6 += v6.x; ay6 += v6.y;  ax7 += v7.x; ay7 += v7.y;
  }
  if (j + 4 <= end){
    const int s0 = csr[j+0], s1 = csr[j+1], s2 = csr[j+2], s3 = csr[j+3];
    const float2 v0 = *(const float2*)&feat[(size_t)s0 * 128 + lo];
    const float2 v1 = *(const float2*)&feat[(size_t)s1 * 128 + lo];
    const float2 v2 = *(const float2*)&feat[(size_t)s2 * 128 + lo];
    const float2 v3 = *(const float2*)&feat[(size_t)s3 * 128 + lo];
    ax0 += v0.x; ay0 += v0.y;  ax1 += v1.x; ay1 += v1.y;
    ax2 += v2.x; ay2 += v2.y;  ax3 += v3.x; ay3 += v3.y;
    j += 4;
  }
  for (; j < end; ++j){
    const int s = csr[j];
    const float2 v = *(const float2*)&feat[(size_t)s * 128 + lo];
    ax4 += v.x; ay4 += v.y;
  }

  const float ic = inv_cnt[node];
  float2 o;
  o.x = (((ax0 + ax1) + (ax2 + ax3)) + ((ax4 + ax5) + (ax6 + ax7))) * ic;
  o.y = (((ay0 + ay1) + (ay2 + ay3)) + ((ay4 + ay5) + (ay6 + ay7))) * ic;
  *(float2*)&outb[(size_t)node * 128 + lo] = o;
}

// ---------------- weight pack + bf16 hi/lo split, FRAGMENT-MAJOR ----------------
__global__ void k_wcs(const float* __restrict__ wl, const float* __restrict__ wr,
                      short* __restrict__ bfr){
  int id = blockIdx.x * 256 + threadIdx.x;
  if (id >= 128 * 256) return;
  int c = id >> 8, k = id & 255;
  float w = (k < 128) ? wl[c * 128 + k] : wr[c * 128 + (k - 128)];
  unsigned short h = bf16_rn(w);
  float hf = __uint_as_float((unsigned)h << 16);
  unsigned short l = bf16_rn(w - hf);
  const int nt = c >> 4, mrow = c & 15;
  const int ks = k >> 5, kgrp = (k >> 3) & 3, j = k & 7;
  const int lane = kgrp * 16 + mrow;
  const size_t fbase = (size_t)((ks * 8 + nt) * 2) * 512 + lane * 8 + j;
  bfr[fbase] = (short)h;
  bfr[fbase + 512] = (short)l;
}

// ---------------- MFMA GEMM: out = prelu([A0|A1] @ W^T + b) ----------------
__global__ __launch_bounds__(256) void k_gemm_mfma(const float* __restrict__ A0,
                                                   const float* __restrict__ A1,
                                                   const short* __restrict__ bfr,
                                                   const float* __restrict__ bias,
                                                   const float* __restrict__ alpha_p,
                                                   float* __restrict__ out,
                                                   int n){
  const int t = threadIdx.x;
  const int lane = t & 63;
  const int wv = t >> 6;
  const int nodeBase = blockIdx.x * 64 + wv * 16;
  const int mrow = lane & 15;
  const int kgrp = lane >> 4;

  int node = nodeBase + mrow;
  if (node > n - 1) node = n - 1;
  const size_t arow = (size_t)node * 128;

  const short8* __restrict__ Bf = (const short8*)bfr;

  f32x4 acc[8];
  #pragma unroll
  for (int i = 0; i < 8; ++i) acc[i] = (f32x4){0.f, 0.f, 0.f, 0.f};

  #pragma unroll
  for (int ks = 0; ks < 8; ++ks){
    const float* __restrict__ Asrc = (ks < 4) ? A0 : A1;
    const int kk = (ks & 3) * 32 + kgrp * 8;
    const float4 v0 = *(const float4*)&Asrc[arow + kk];
    const float4 v1 = *(const float4*)&Asrc[arow + kk + 4];

    short8 bh[8], bl[8];
    const int fb = ks * 16;
    #pragma unroll
    for (int nt = 0; nt < 8; ++nt){
      bh[nt] = Bf[(size_t)(fb + nt * 2 + 0) * 64 + lane];
      bl[nt] = Bf[(size_t)(fb + nt * 2 + 1) * 64 + lane];
    }

    const float av[8] = {v0.x, v0.y, v0.z, v0.w, v1.x, v1.y, v1.z, v1.w};
    short8 ah, al;
    #pragma unroll
    for (int i = 0; i < 8; ++i){
      unsigned short h = bf16_rn(av[i]);
      ah[i] = (short)h;
      float hf = __uint_as_float((unsigned)h << 16);
      al[i] = (short)bf16_rn(av[i] - hf);
    }

    #pragma unroll
    for (int nt = 0; nt < 8; ++nt){
      mfma_bf16(acc[nt], ah, bh[nt]);
      mfma_bf16(acc[nt], al, bh[nt]);
      mfma_bf16(acc[nt], ah, bl[nt]);
    }
  }

  const float alpha = *alpha_p;
  #pragma unroll
  for (int nt = 0; nt < 8; ++nt){
    const int col = nt * 16 + mrow;
    const float bv = bias[col];
    #pragma unroll
    for (int j = 0; j < 4; ++j){
      const int onode = nodeBase + kgrp * 4 + j;
      if (onode < n){
        float v = acc[nt][j] + bv;
        v = fmaxf(v, 0.f) + alpha * fminf(v, 0.f);
        out[(size_t)onode * 128 + col] = v;
      }
    }
  }
}

// ---------------- layer-3 fusion ----------------
__global__ void k_u(const float* __restrict__ w3l, const float* __restrict__ w3r,
                    const float* __restrict__ b3, const float* __restrict__ wp,
                    const float* __restrict__ bp, float* __restrict__ u){
  int k = threadIdx.x;
  float sl = 0.f, sr = 0.f;
  for (int o = 0; o < 64; ++o){
    float w = wp[o];
    sl = fmaf(w, w3l[o * 128 + k], sl);
    sr = fmaf(w, w3r[o * 128 + k], sr);
  }
  u[k] = sl; u[128 + k] = sr;
  if (k == 0){
    float c = bp[0];
    for (int o = 0; o < 64; ++o) c = fmaf(wp[o], b3[o], c);
    u[256] = c;
  }
}

__global__ __launch_bounds__(256) void k_dot(const float* __restrict__ h,
                                             const float* __restrict__ u,
                                             float* __restrict__ s,
                                             float* __restrict__ partial, int n){
  const int lane = threadIdx.x & 63;
  const int i = blockIdx.x * 4 + (threadIdx.x >> 6);
  if (i >= n) return;
  const float2 hv  = *(const float2*)&h[(size_t)i * 128 + lane * 2];
  const float2 ulv = *(const float2*)&u[lane * 2];
  const float2 urv = *(const float2*)&u[128 + lane * 2];
  float sv = hv.x * ulv.x + hv.y * ulv.y;
  float tv = hv.x * urv.x + hv.y * urv.y;
  #pragma unroll
  for (int off = 32; off > 0; off >>= 1){
    sv += __shfl_down(sv, off);
    tv += __shfl_down(tv, off);
  }
  if (lane == 0){ s[i] = sv; partial[i] = tv + u[256]; }
}

__global__ __launch_bounds__(256) void k_final(const float* __restrict__ s, const float* __restrict__ partial,
                        const unsigned short* __restrict__ csr, const int* __restrict__ row_ptr,
                        const float* __restrict__ inv_cnt, float* __restrict__ out, int n){
  const int t = blockIdx.x * blockDim.x + threadIdx.x;
  const int node = t >> 2;
  const int sub = t & 3;
  if (node >= n) return;
  const int b = row_ptr[node], e = row_ptr[node + 1];
  float a0 = 0.f, a1 = 0.f;
  int j = b + sub;
  for (; j + 4 < e; j += 8){
    a0 += s[csr[j]];
    a1 += s[csr[j + 4]];
  }
  if (j < e) a0 += s[csr[j]];
  float acc = a0 + a1;
  acc += __shfl_down(acc, 1);
  acc += __shfl_down(acc, 2);
  if (sub == 0) out[node] = acc * inv_cnt[node] + partial[node];
}

// ---------------- launch ----------------
extern "C" void kernel_launch(void* const* d_in, const int* in_sizes, int n_in,
                              void* d_out, int out_size, void* d_ws, size_t ws_size,
                              hipStream_t stream){
  const float* x   = (const float*)d_in[0];
  const int*   ei  = (const int*)d_in[1];
  const float* w1l = (const float*)d_in[2];
  const float* w1r = (const float*)d_in[3];
  const float* b1  = (const float*)d_in[4];
  const float* w2l = (const float*)d_in[5];
  const float* w2r = (const float*)d_in[6];
  const float* b2  = (const float*)d_in[7];
  const float* w3l = (const float*)d_in[8];
  const float* w3r = (const float*)d_in[9];
  const float* b3  = (const float*)d_in[10];
  const float* ap  = (const float*)d_in[11];
  const float* wp  = (const float*)d_in[12];
  const float* bp  = (const float*)d_in[13];

  const int n = out_size;              // 50000 nodes
  const int E = in_sizes[1] / 2;       // 800000 edges
  const int* srcI = ei;
  const int* dstI = ei + E;

  const int ntiles = (E + 2047) / 2048;
  const int nb = (n + 255) >> 8;       // 196 buckets

  char* base = (char*)d_ws;
  size_t off = 0;
  auto take = [&](size_t bytes) -> char* {
    off = (off + 255) & ~(size_t)255;
    char* p = base + off;
    off += bytes;
    return p;
  };
  int*      blk_hist = (int*)   take((size_t)nb * ntiles * 4);
  int*      tot      = (int*)   take((size_t)nb * 4);
  int*      bbase    = (int*)   take(((size_t)nb + 1) * 4);
  unsigned* ebuf     = (unsigned*)take((size_t)E * 4);
  int*      rowp     = (int*)   take(((size_t)n + 1) * 4);
  float*    inv      = (float*) take((size_t)n * 4);
  unsigned short* csr = (unsigned short*)take((size_t)E * 2);
  float*    B1   = (float*)take((size_t)n * 128 * 4);
  float*    B2   = (float*)take((size_t)n * 128 * 4);
  float*    sbuf = (float*)take((size_t)n * 4);
  float*    pbuf = (float*)take((size_t)n * 4);
  float*    u    = (float*)take(257 * 4);
  short*    bfr  = (short*)take((size_t)128 * 512 * 2);
  (void)ws_size; (void)n_in;

  // CSR build: counting sort, no global atomics, coalesced writes
  k_bcount<<<ntiles, 256, 0, stream>>>(dstI, E, nb, ntiles, blk_hist);
  k_bscan <<<nb,     256, 0, stream>>>(blk_hist, nb, ntiles, tot);
  k_btot  <<<1,      256, 0, stream>>>(tot, nb, bbase);
  k_bscat <<<ntiles, 256, 0, stream>>>(srcI, dstI, E, nb, ntiles, blk_hist, bbase, ebuf);
  k_csrfin<<<nb,     256, 0, stream>>>(ebuf, bbase, n, E, nb, rowp, inv, csr);

  const int aggGrid  = (n * 64 + 255) / 256;
  const int gemmGrid = (n + 63) / 64;

  // layer 1: h1 = prelu([agg(x)|x] @ W1 + b1)
  k_agg      <<<aggGrid, 256, 0, stream>>>(x, csr, rowp, inv, B1, n);
  k_wcs      <<<128, 256, 0, stream>>>(w1l, w1r, bfr);
  k_gemm_mfma<<<gemmGrid, 256, 0, stream>>>(B1, x, bfr, b1, ap, B2, n);

  // layer 2: h2 = prelu([agg(h1)|h1] @ W2 + b2)
  k_agg      <<<aggGrid, 256, 0, stream>>>(B2, csr, rowp, inv, B1, n);
  k_wcs      <<<128, 256, 0, stream>>>(w2l, w2r, bfr);
  k_gemm_mfma<<<gemmGrid, 256, 0, stream>>>(B1, B2, bfr, b2, ap, B2, n);

  // layer 3 + head, fused via u_l = wp@w3l, u_r = wp@w3r
  k_u    <<<1, 128, 0, stream>>>(w3l, w3r, b3, wp, bp, u);
  k_dot  <<<(n + 3) / 4, 256, 0, stream>>>(B2, u, sbuf, pbuf, n);
  k_final<<<(n * 4 + 255) / 256, 256, 0, stream>>>(sbuf, pbuf, csr, rowp, inv, (float*)d_out, n);
}

// Round 8
// 190.469 us; speedup vs baseline: 2.5309x; 1.1782x over previous
//
#include <hip/hip_runtime.h>
#include <cstdint>
#include <cstddef>

typedef float f32x4 __attribute__((ext_vector_type(4)));
typedef short short8 __attribute__((ext_vector_type(8)));
typedef __bf16 bf16x8 __attribute__((ext_vector_type(8)));

__device__ __forceinline__ void mfma_bf16(f32x4& d, short8 a, short8 b){
  d = __builtin_amdgcn_mfma_f32_16x16x32_bf16(
        __builtin_bit_cast(bf16x8, a), __builtin_bit_cast(bf16x8, b), d, 0, 0, 0);
}

__device__ __forceinline__ unsigned short bf16_rn(float f){
  unsigned u = __float_as_uint(f);
  unsigned r = (u + 0x7FFF + ((u >> 16) & 1)) >> 16;
  return (unsigned short)r;
}

// 256-thread exclusive block scan (4 waves).
__device__ __forceinline__ int blockScan256Excl(int v, int* wsum){
  const int lane = threadIdx.x & 63, wv = threadIdx.x >> 6;
  int x = v;
  #pragma unroll
  for (int off = 1; off < 64; off <<= 1){
    int y = __shfl_up(x, off);
    if (lane >= off) x += y;
  }
  if (lane == 63) wsum[wv] = x;
  __syncthreads();
  int woff = 0;
  #pragma unroll
  for (int w = 0; w < 4; ++w) woff += (w < wv) ? wsum[w] : 0;
  return woff + x - v;
}

// ================= CSR build: two-level counting sort (no global atomics) =================
__global__ __launch_bounds__(256) void k_bcount(const int* __restrict__ dst, int E, int nb, int ntiles,
                                                int* __restrict__ blk_hist){
  __shared__ int h[256];
  const int tile = blockIdx.x;
  h[threadIdx.x] = 0;
  __syncthreads();
  const int base = tile * 2048;
  const int end = min(base + 2048, E);
  for (int i = base + threadIdx.x; i < end; i += 256)
    atomicAdd(&h[dst[i] >> 8], 1);
  __syncthreads();
  const int b = threadIdx.x;
  if (b < nb) blk_hist[(size_t)b * ntiles + tile] = h[b];
}

__global__ __launch_bounds__(256) void k_bscan(int* __restrict__ blk_hist, int nb, int ntiles,
                                               int* __restrict__ tot){
  __shared__ int wsum[4];
  __shared__ int carry;
  const int b = blockIdx.x;
  int* row = blk_hist + (size_t)b * ntiles;
  if (threadIdx.x == 0) carry = 0;
  __syncthreads();
  const int lane = threadIdx.x & 63, wv = threadIdx.x >> 6;
  for (int base = 0; base < ntiles; base += 256){
    const int i = base + threadIdx.x;
    const int v = (i < ntiles) ? row[i] : 0;
    int x = v;
    #pragma unroll
    for (int off = 1; off < 64; off <<= 1){
      int y = __shfl_up(x, off);
      if (lane >= off) x += y;
    }
    if (lane == 63) wsum[wv] = x;
    __syncthreads();
    int woff = 0;
    #pragma unroll
    for (int w = 0; w < 4; ++w) woff += (w < wv) ? wsum[w] : 0;
    const int incl = carry + woff + x;
    if (i < ntiles) row[i] = incl - v;
    __syncthreads();
    if (threadIdx.x == 255) carry = incl;
    __syncthreads();
  }
  if (threadIdx.x == 0) tot[b] = carry;
}

__global__ __launch_bounds__(256) void k_btot(const int* __restrict__ tot, int nb,
                                              int* __restrict__ bucket_base){
  __shared__ int wsum[4];
  const int t = threadIdx.x;
  const int v = (t < nb) ? tot[t] : 0;
  const int e = blockScan256Excl(v, wsum);
  if (t <= nb) bucket_base[t] = e;
}

__global__ __launch_bounds__(256) void k_bscat(const int* __restrict__ src, const int* __restrict__ dst,
                                               int E, int nb, int ntiles,
                                               const int* __restrict__ blk_off,
                                               const int* __restrict__ bucket_base,
                                               unsigned* __restrict__ ebuf){
  __shared__ int cnt[256];
  __shared__ int lofs[256];
  __shared__ int gbase[256];
  __shared__ unsigned sorted[2048];
  __shared__ unsigned char sb[2048];
  __shared__ int wsum[4];
  const int tile = blockIdx.x;
  cnt[threadIdx.x] = 0;
  __syncthreads();
  const int base = tile * 2048;
  const int end = min(base + 2048, E);
  const int m = end - base;

  int rank_[8]; int b_[8]; unsigned v_[8];
  #pragma unroll
  for (int k = 0; k < 8; ++k){
    const int j = threadIdx.x + k * 256;
    if (base + j < end){
      const int d = dst[base + j];
      const int s = src[base + j];
      const int b = d >> 8;
      b_[k] = b;
      v_[k] = ((unsigned)(d & 255) << 16) | (unsigned)s;
      rank_[k] = atomicAdd(&cnt[b], 1);
    } else b_[k] = -1;
  }
  __syncthreads();
  const int ex = blockScan256Excl(cnt[threadIdx.x], wsum);
  lofs[threadIdx.x] = ex;
  if (threadIdx.x < nb)
    gbase[threadIdx.x] = bucket_base[threadIdx.x] + blk_off[(size_t)threadIdx.x * ntiles + tile];
  __syncthreads();
  #pragma unroll
  for (int k = 0; k < 8; ++k){
    if (b_[k] >= 0){
      const int p = lofs[b_[k]] + rank_[k];
      sorted[p] = v_[k];
      sb[p] = (unsigned char)b_[k];
    }
  }
  __syncthreads();
  for (int j = threadIdx.x; j < m; j += 256){
    const int b = sb[j];
    ebuf[gbase[b] + (j - lofs[b])] = sorted[j];
  }
}

__global__ __launch_bounds__(256) void k_csrfin(const unsigned* __restrict__ ebuf,
                                                const int* __restrict__ bucket_base,
                                                int n, int E, int nb,
                                                int* __restrict__ row_ptr,
                                                float* __restrict__ inv,
                                                unsigned short* __restrict__ csr){
  __shared__ int hist[256], excl[256], cursor[256];
  __shared__ int wsum[4];
  __shared__ unsigned vals[8192];
  __shared__ unsigned short sorted[8192];
  const int b = blockIdx.x;
  const int ebase = bucket_base[b];
  const int ecnt = bucket_base[b + 1] - ebase;
  const int t = threadIdx.x;
  hist[t] = 0;
  __syncthreads();
  for (int j = t; j < ecnt; j += 256){
    const unsigned v = ebuf[ebase + j];
    vals[j] = v;
    atomicAdd(&hist[v >> 16], 1);
  }
  __syncthreads();
  const int ex = blockScan256Excl(hist[t], wsum);
  excl[t] = ex;
  cursor[t] = ex;
  const int node = b * 256 + t;
  if (node < n){
    row_ptr[node] = ebase + ex;
    const int c = hist[t];
    inv[node] = 1.0f / (float)(c > 0 ? c : 1);
  }
  if (b == nb - 1 && t == 0) row_ptr[n] = E;
  __syncthreads();
  for (int j = t; j < ecnt; j += 256){
    const unsigned v = vals[j];
    const int pos = atomicAdd(&cursor[v >> 16], 1);
    sorted[pos] = (unsigned short)(v & 0xFFFFu);
  }
  __syncthreads();
  for (int j = t; j < ecnt; j += 256)
    csr[ebase + j] = sorted[j];
}

// ---------------- fp32 -> bf16 table convert ----------------
__global__ __launch_bounds__(256) void k_cvt(const float* __restrict__ in,
                                             unsigned short* __restrict__ out, int total){
  const int i = (blockIdx.x * 256 + threadIdx.x) * 4;
  if (i >= total) return;
  const float4 v = *(const float4*)&in[i];
  ushort2 a, b;
  a.x = bf16_rn(v.x); a.y = bf16_rn(v.y);
  b.x = bf16_rn(v.z); b.y = bf16_rn(v.w);
  *(ushort2*)&out[i] = a;
  *(ushort2*)&out[i + 2] = b;
}

// ---------------- mean aggregation: bf16 gather, fp32 accumulate ----------------
// one wave per node; lane covers cols {2*lane, 2*lane+1} = one uint (2 bf16) per row
__global__ __launch_bounds__(256) void k_aggb(const unsigned short* __restrict__ featb,
                                              const unsigned short* __restrict__ csr,
                                              const int* __restrict__ row_ptr,
                                              const float* __restrict__ inv_cnt,
                                              float* __restrict__ outb, int n){
  const int lane = threadIdx.x & 63;
  const int node = (blockIdx.x * blockDim.x + threadIdx.x) >> 6;
  if (node >= n) return;
  const int beg = row_ptr[node];
  const int end = row_ptr[node + 1];
  const unsigned* __restrict__ fb = (const unsigned*)featb;   // [node][64]

  float ax0=0.f, ay0=0.f, ax1=0.f, ay1=0.f, ax2=0.f, ay2=0.f, ax3=0.f, ay3=0.f;
  float ax4=0.f, ay4=0.f, ax5=0.f, ay5=0.f, ax6=0.f, ay6=0.f, ax7=0.f, ay7=0.f;

  int j = beg;
  for (; j + 8 <= end; j += 8){
    const int s0 = csr[j+0], s1 = csr[j+1], s2 = csr[j+2], s3 = csr[j+3];
    const int s4 = csr[j+4], s5 = csr[j+5], s6 = csr[j+6], s7 = csr[j+7];
    const unsigned u0 = fb[(size_t)s0 * 64 + lane];
    const unsigned u1 = fb[(size_t)s1 * 64 + lane];
    const unsigned u2 = fb[(size_t)s2 * 64 + lane];
    const unsigned u3 = fb[(size_t)s3 * 64 + lane];
    const unsigned u4 = fb[(size_t)s4 * 64 + lane];
    const unsigned u5 = fb[(size_t)s5 * 64 + lane];
    const unsigned u6 = fb[(size_t)s6 * 64 + lane];
    const unsigned u7 = fb[(size_t)s7 * 64 + lane];
    ax0 += __uint_as_float(u0 << 16); ay0 += __uint_as_float(u0 & 0xFFFF0000u);
    ax1 += __uint_as_float(u1 << 16); ay1 += __uint_as_float(u1 & 0xFFFF0000u);
    ax2 += __uint_as_float(u2 << 16); ay2 += __uint_as_float(u2 & 0xFFFF0000u);
    ax3 += __uint_as_float(u3 << 16); ay3 += __uint_as_float(u3 & 0xFFFF0000u);
    ax4 += __uint_as_float(u4 << 16); ay4 += __uint_as_float(u4 & 0xFFFF0000u);
    ax5 += __uint_as_float(u5 << 16); ay5 += __uint_as_float(u5 & 0xFFFF0000u);
    ax6 += __uint_as_float(u6 << 16); ay6 += __uint_as_float(u6 & 0xFFFF0000u);
    ax7 += __uint_as_float(u7 << 16); ay7 += __uint_as_float(u7 & 0xFFFF0000u);
  }
  if (j + 4 <= end){
    const int s0 = csr[j+0], s1 = csr[j+1], s2 = csr[j+2], s3 = csr[j+3];
    const unsigned u0 = fb[(size_t)s0 * 64 + lane];
    const unsigned u1 = fb[(size_t)s1 * 64 + lane];
    const unsigned u2 = fb[(size_t)s2 * 64 + lane];
    const unsigned u3 = fb[(size_t)s3 * 64 + lane];
    ax0 += __uint_as_float(u0 << 16); ay0 += __uint_as_float(u0 & 0xFFFF0000u);
    ax1 += __uint_as_float(u1 << 16); ay1 += __uint_as_float(u1 & 0xFFFF0000u);
    ax2 += __uint_as_float(u2 << 16); ay2 += __uint_as_float(u2 & 0xFFFF0000u);
    ax3 += __uint_as_float(u3 << 16); ay3 += __uint_as_float(u3 & 0xFFFF0000u);
    j += 4;
  }
  for (; j < end; ++j){
    const int s = csr[j];
    const unsigned u = fb[(size_t)s * 64 + lane];
    ax4 += __uint_as_float(u << 16); ay4 += __uint_as_float(u & 0xFFFF0000u);
  }

  const float ic = inv_cnt[node];
  float2 o;
  o.x = (((ax0 + ax1) + (ax2 + ax3)) + ((ax4 + ax5) + (ax6 + ax7))) * ic;
  o.y = (((ay0 + ay1) + (ay2 + ay3)) + ((ay4 + ay5) + (ay6 + ay7))) * ic;
  *(float2*)&outb[(size_t)node * 128 + lane * 2] = o;
}

// ---------------- weight pack + bf16 hi/lo split, FRAGMENT-MAJOR ----------------
__global__ void k_wcs(const float* __restrict__ wl, const float* __restrict__ wr,
                      short* __restrict__ bfr){
  int id = blockIdx.x * 256 + threadIdx.x;
  if (id >= 128 * 256) return;
  int c = id >> 8, k = id & 255;
  float w = (k < 128) ? wl[c * 128 + k] : wr[c * 128 + (k - 128)];
  unsigned short h = bf16_rn(w);
  float hf = __uint_as_float((unsigned)h << 16);
  unsigned short l = bf16_rn(w - hf);
  const int nt = c >> 4, mrow = c & 15;
  const int ks = k >> 5, kgrp = (k >> 3) & 3, j = k & 7;
  const int lane = kgrp * 16 + mrow;
  const size_t fbase = (size_t)((ks * 8 + nt) * 2) * 512 + lane * 8 + j;
  bfr[fbase] = (short)h;
  bfr[fbase + 512] = (short)l;
}

// ---------------- MFMA GEMM: out = prelu([A0|A1] @ W^T + b), optional bf16 copy ----------------
__global__ __launch_bounds__(256) void k_gemm_mfma(const float* __restrict__ A0,
                                                   const float* __restrict__ A1,
                                                   const short* __restrict__ bfr,
                                                   const float* __restrict__ bias,
                                                   const float* __restrict__ alpha_p,
                                                   float* __restrict__ out,
                                                   unsigned short* __restrict__ outb16, // may be null
                                                   int n){
  const int t = threadIdx.x;
  const int lane = t & 63;
  const int wv = t >> 6;
  const int nodeBase = blockIdx.x * 64 + wv * 16;
  const int mrow = lane & 15;
  const int kgrp = lane >> 4;

  int node = nodeBase + mrow;
  if (node > n - 1) node = n - 1;
  const size_t arow = (size_t)node * 128;

  const short8* __restrict__ Bf = (const short8*)bfr;

  f32x4 acc[8];
  #pragma unroll
  for (int i = 0; i < 8; ++i) acc[i] = (f32x4){0.f, 0.f, 0.f, 0.f};

  #pragma unroll
  for (int ks = 0; ks < 8; ++ks){
    const float* __restrict__ Asrc = (ks < 4) ? A0 : A1;
    const int kk = (ks & 3) * 32 + kgrp * 8;
    const float4 v0 = *(const float4*)&Asrc[arow + kk];
    const float4 v1 = *(const float4*)&Asrc[arow + kk + 4];

    short8 bh[8], bl[8];
    const int fb = ks * 16;
    #pragma unroll
    for (int nt = 0; nt < 8; ++nt){
      bh[nt] = Bf[(size_t)(fb + nt * 2 + 0) * 64 + lane];
      bl[nt] = Bf[(size_t)(fb + nt * 2 + 1) * 64 + lane];
    }

    const float av[8] = {v0.x, v0.y, v0.z, v0.w, v1.x, v1.y, v1.z, v1.w};
    short8 ah, al;
    #pragma unroll
    for (int i = 0; i < 8; ++i){
      unsigned short h = bf16_rn(av[i]);
      ah[i] = (short)h;
      float hf = __uint_as_float((unsigned)h << 16);
      al[i] = (short)bf16_rn(av[i] - hf);
    }

    #pragma unroll
    for (int nt = 0; nt < 8; ++nt){
      mfma_bf16(acc[nt], ah, bh[nt]);
      mfma_bf16(acc[nt], al, bh[nt]);
      mfma_bf16(acc[nt], ah, bl[nt]);
    }
  }

  const float alpha = *alpha_p;
  #pragma unroll
  for (int nt = 0; nt < 8; ++nt){
    const int col = nt * 16 + mrow;
    const float bv = bias[col];
    #pragma unroll
    for (int j = 0; j < 4; ++j){
      const int onode = nodeBase + kgrp * 4 + j;
      if (onode < n){
        float v = acc[nt][j] + bv;
        v = fmaxf(v, 0.f) + alpha * fminf(v, 0.f);
        out[(size_t)onode * 128 + col] = v;
        if (outb16) outb16[(size_t)onode * 128 + col] = bf16_rn(v);
      }
    }
  }
}

// ---------------- layer-3 fusion ----------------
__global__ void k_u(const float* __restrict__ w3l, const float* __restrict__ w3r,
                    const float* __restrict__ b3, const float* __restrict__ wp,
                    const float* __restrict__ bp, float* __restrict__ u){
  int k = threadIdx.x;
  float sl = 0.f, sr = 0.f;
  for (int o = 0; o < 64; ++o){
    float w = wp[o];
    sl = fmaf(w, w3l[o * 128 + k], sl);
    sr = fmaf(w, w3r[o * 128 + k], sr);
  }
  u[k] = sl; u[128 + k] = sr;
  if (k == 0){
    float c = bp[0];
    for (int o = 0; o < 64; ++o) c = fmaf(wp[o], b3[o], c);
    u[256] = c;
  }
}

__global__ __launch_bounds__(256) void k_dot(const float* __restrict__ h,
                                             const float* __restrict__ u,
                                             float* __restrict__ s,
                                             float* __restrict__ partial, int n){
  const int lane = threadIdx.x & 63;
  const int i = blockIdx.x * 4 + (threadIdx.x >> 6);
  if (i >= n) return;
  const float2 hv  = *(const float2*)&h[(size_t)i * 128 + lane * 2];
  const float2 ulv = *(const float2*)&u[lane * 2];
  const float2 urv = *(const float2*)&u[128 + lane * 2];
  float sv = hv.x * ulv.x + hv.y * ulv.y;
  float tv = hv.x * urv.x + hv.y * urv.y;
  #pragma unroll
  for (int off = 32; off > 0; off >>= 1){
    sv += __shfl_down(sv, off);
    tv += __shfl_down(tv, off);
  }
  if (lane == 0){ s[i] = sv; partial[i] = tv + u[256]; }
}

__global__ __launch_bounds__(256) void k_final(const float* __restrict__ s, const float* __restrict__ partial,
                        const unsigned short* __restrict__ csr, const int* __restrict__ row_ptr,
                        const float* __restrict__ inv_cnt, float* __restrict__ out, int n){
  const int t = blockIdx.x * blockDim.x + threadIdx.x;
  const int node = t >> 2;
  const int sub = t & 3;
  if (node >= n) return;
  const int b = row_ptr[node], e = row_ptr[node + 1];
  float a0 = 0.f, a1 = 0.f;
  int j = b + sub;
  for (; j + 4 < e; j += 8){
    a0 += s[csr[j]];
    a1 += s[csr[j + 4]];
  }
  if (j < e) a0 += s[csr[j]];
  float acc = a0 + a1;
  acc += __shfl_down(acc, 1);
  acc += __shfl_down(acc, 2);
  if (sub == 0) out[node] = acc * inv_cnt[node] + partial[node];
}

// ---------------- launch ----------------
extern "C" void kernel_launch(void* const* d_in, const int* in_sizes, int n_in,
                              void* d_out, int out_size, void* d_ws, size_t ws_size,
                              hipStream_t stream){
  const float* x   = (const float*)d_in[0];
  const int*   ei  = (const int*)d_in[1];
  const float* w1l = (const float*)d_in[2];
  const float* w1r = (const float*)d_in[3];
  const float* b1  = (const float*)d_in[4];
  const float* w2l = (const float*)d_in[5];
  const float* w2r = (const float*)d_in[6];
  const float* b2  = (const float*)d_in[7];
  const float* w3l = (const float*)d_in[8];
  const float* w3r = (const float*)d_in[9];
  const float* b3  = (const float*)d_in[10];
  const float* ap  = (const float*)d_in[11];
  const float* wp  = (const float*)d_in[12];
  const float* bp  = (const float*)d_in[13];

  const int n = out_size;              // 50000 nodes
  const int E = in_sizes[1] / 2;       // 800000 edges
  const int* srcI = ei;
  const int* dstI = ei + E;

  const int ntiles = (E + 2047) / 2048;
  const int nb = (n + 255) >> 8;       // 196 buckets

  char* base = (char*)d_ws;
  size_t off = 0;
  auto take = [&](size_t bytes) -> char* {
    off = (off + 255) & ~(size_t)255;
    char* p = base + off;
    off += bytes;
    return p;
  };
  int*      blk_hist = (int*)   take((size_t)nb * ntiles * 4);
  int*      tot      = (int*)   take((size_t)nb * 4);
  int*      bbase    = (int*)   take(((size_t)nb + 1) * 4);
  unsigned* ebuf     = (unsigned*)take((size_t)E * 4);
  int*      rowp     = (int*)   take(((size_t)n + 1) * 4);
  float*    inv      = (float*) take((size_t)n * 4);
  unsigned short* csr = (unsigned short*)take((size_t)E * 2);
  float*    B1   = (float*)take((size_t)n * 128 * 4);
  float*    B2   = (float*)take((size_t)n * 128 * 4);
  unsigned short* xb  = (unsigned short*)take((size_t)n * 128 * 2);
  unsigned short* h1b = (unsigned short*)take((size_t)n * 128 * 2);
  float*    sbuf = (float*)take((size_t)n * 4);
  float*    pbuf = (float*)take((size_t)n * 4);
  float*    u    = (float*)take(257 * 4);
  short*    bfr  = (short*)take((size_t)128 * 512 * 2);
  (void)ws_size; (void)n_in;

  // CSR build: counting sort, no global atomics, coalesced writes
  k_bcount<<<ntiles, 256, 0, stream>>>(dstI, E, nb, ntiles, blk_hist);
  k_bscan <<<nb,     256, 0, stream>>>(blk_hist, nb, ntiles, tot);
  k_btot  <<<1,      256, 0, stream>>>(tot, nb, bbase);
  k_bscat <<<ntiles, 256, 0, stream>>>(srcI, dstI, E, nb, ntiles, blk_hist, bbase, ebuf);
  k_csrfin<<<nb,     256, 0, stream>>>(ebuf, bbase, n, E, nb, rowp, inv, csr);

  // bf16 feature table for gathers
  k_cvt<<<(n * 128 / 4 + 255) / 256, 256, 0, stream>>>(x, xb, n * 128);

  const int aggGrid  = (n * 64 + 255) / 256;
  const int gemmGrid = (n + 63) / 64;

  // layer 1: h1 = prelu([agg(x)|x] @ W1 + b1)   (h1 also emitted in bf16 for layer-2 gather)
  k_aggb     <<<aggGrid, 256, 0, stream>>>(xb, csr, rowp, inv, B1, n);
  k_wcs      <<<128, 256, 0, stream>>>(w1l, w1r, bfr);
  k_gemm_mfma<<<gemmGrid, 256, 0, stream>>>(B1, x, bfr, b1, ap, B2, h1b, n);

  // layer 2: h2 = prelu([agg(h1)|h1] @ W2 + b2)
  k_aggb     <<<aggGrid, 256, 0, stream>>>(h1b, csr, rowp, inv, B1, n);
  k_wcs      <<<128, 256, 0, stream>>>(w2l, w2r, bfr);
  k_gemm_mfma<<<gemmGrid, 256, 0, stream>>>(B1, B2, bfr, b2, ap, B2, (unsigned short*)nullptr, n);

  // layer 3 + head, fused via u_l = wp@w3l, u_r = wp@w3r
  k_u    <<<1, 128, 0, stream>>>(w3l, w3r, b3, wp, bp, u);
  k_dot  <<<(n + 3) / 4, 256, 0, stream>>>(B2, u, sbuf, pbuf, n);
  k_final<<<(n * 4 + 255) / 256, 256, 0, stream>>>(sbuf, pbuf, csr, rowp, inv, (float*)d_out, n);
}

// Round 9
// 178.718 us; speedup vs baseline: 2.6973x; 1.0658x over previous
//
#include <hip/hip_runtime.h>
#include <cstdint>
#include <cstddef>

typedef float f32x4 __attribute__((ext_vector_type(4)));
typedef short short8 __attribute__((ext_vector_type(8)));
typedef __bf16 bf16x8 __attribute__((ext_vector_type(8)));

__device__ __forceinline__ void mfma_bf16(f32x4& d, short8 a, short8 b){
  d = __builtin_amdgcn_mfma_f32_16x16x32_bf16(
        __builtin_bit_cast(bf16x8, a), __builtin_bit_cast(bf16x8, b), d, 0, 0, 0);
}

__device__ __forceinline__ unsigned short bf16_rn(float f){
  unsigned u = __float_as_uint(f);
  unsigned r = (u + 0x7FFF + ((u >> 16) & 1)) >> 16;
  return (unsigned short)r;
}

// 256-thread exclusive block scan (4 waves).
__device__ __forceinline__ int blockScan256Excl(int v, int* wsum){
  const int lane = threadIdx.x & 63, wv = threadIdx.x >> 6;
  int x = v;
  #pragma unroll
  for (int off = 1; off < 64; off <<= 1){
    int y = __shfl_up(x, off);
    if (lane >= off) x += y;
  }
  if (lane == 63) wsum[wv] = x;
  __syncthreads();
  int woff = 0;
  #pragma unroll
  for (int w = 0; w < 4; ++w) woff += (w < wv) ? wsum[w] : 0;
  return woff + x - v;
}

// ================= CSR build: two-level counting sort (no global atomics) =================
__global__ __launch_bounds__(256) void k_bcount(const int* __restrict__ dst, int E, int nb, int ntiles,
                                                int* __restrict__ blk_hist){
  __shared__ int h[256];
  const int tile = blockIdx.x;
  h[threadIdx.x] = 0;
  __syncthreads();
  const int base = tile * 2048;
  const int end = min(base + 2048, E);
  for (int i = base + threadIdx.x; i < end; i += 256)
    atomicAdd(&h[dst[i] >> 8], 1);
  __syncthreads();
  const int b = threadIdx.x;
  if (b < nb) blk_hist[(size_t)b * ntiles + tile] = h[b];
}

__global__ __launch_bounds__(256) void k_bscan(int* __restrict__ blk_hist, int nb, int ntiles,
                                               int* __restrict__ tot){
  __shared__ int wsum[4];
  __shared__ int carry;
  const int b = blockIdx.x;
  int* row = blk_hist + (size_t)b * ntiles;
  if (threadIdx.x == 0) carry = 0;
  __syncthreads();
  const int lane = threadIdx.x & 63, wv = threadIdx.x >> 6;
  for (int base = 0; base < ntiles; base += 256){
    const int i = base + threadIdx.x;
    const int v = (i < ntiles) ? row[i] : 0;
    int x = v;
    #pragma unroll
    for (int off = 1; off < 64; off <<= 1){
      int y = __shfl_up(x, off);
      if (lane >= off) x += y;
    }
    if (lane == 63) wsum[wv] = x;
    __syncthreads();
    int woff = 0;
    #pragma unroll
    for (int w = 0; w < 4; ++w) woff += (w < wv) ? wsum[w] : 0;
    const int incl = carry + woff + x;
    if (i < ntiles) row[i] = incl - v;
    __syncthreads();
    if (threadIdx.x == 255) carry = incl;
    __syncthreads();
  }
  if (threadIdx.x == 0) tot[b] = carry;
}

__global__ __launch_bounds__(256) void k_btot(const int* __restrict__ tot, int nb,
                                              int* __restrict__ bucket_base){
  __shared__ int wsum[4];
  const int t = threadIdx.x;
  const int v = (t < nb) ? tot[t] : 0;
  const int e = blockScan256Excl(v, wsum);
  if (t <= nb) bucket_base[t] = e;
}

__global__ __launch_bounds__(256) void k_bscat(const int* __restrict__ src, const int* __restrict__ dst,
                                               int E, int nb, int ntiles,
                                               const int* __restrict__ blk_off,
                                               const int* __restrict__ bucket_base,
                                               unsigned* __restrict__ ebuf){
  __shared__ int cnt[256];
  __shared__ int lofs[256];
  __shared__ int gbase[256];
  __shared__ unsigned sorted[2048];
  __shared__ unsigned char sb[2048];
  __shared__ int wsum[4];
  const int tile = blockIdx.x;
  cnt[threadIdx.x] = 0;
  __syncthreads();
  const int base = tile * 2048;
  const int end = min(base + 2048, E);
  const int m = end - base;

  int rank_[8]; int b_[8]; unsigned v_[8];
  #pragma unroll
  for (int k = 0; k < 8; ++k){
    const int j = threadIdx.x + k * 256;
    if (base + j < end){
      const int d = dst[base + j];
      const int s = src[base + j];
      const int b = d >> 8;
      b_[k] = b;
      v_[k] = ((unsigned)(d & 255) << 16) | (unsigned)s;
      rank_[k] = atomicAdd(&cnt[b], 1);
    } else b_[k] = -1;
  }
  __syncthreads();
  const int ex = blockScan256Excl(cnt[threadIdx.x], wsum);
  lofs[threadIdx.x] = ex;
  if (threadIdx.x < nb)
    gbase[threadIdx.x] = bucket_base[threadIdx.x] + blk_off[(size_t)threadIdx.x * ntiles + tile];
  __syncthreads();
  #pragma unroll
  for (int k = 0; k < 8; ++k){
    if (b_[k] >= 0){
      const int p = lofs[b_[k]] + rank_[k];
      sorted[p] = v_[k];
      sb[p] = (unsigned char)b_[k];
    }
  }
  __syncthreads();
  for (int j = threadIdx.x; j < m; j += 256){
    const int b = sb[j];
    ebuf[gbase[b] + (j - lofs[b])] = sorted[j];
  }
}

__global__ __launch_bounds__(256) void k_csrfin(const unsigned* __restrict__ ebuf,
                                                const int* __restrict__ bucket_base,
                                                int n, int E, int nb,
                                                int* __restrict__ row_ptr,
                                                float* __restrict__ inv,
                                                unsigned short* __restrict__ csr){
  __shared__ int hist[256], excl[256], cursor[256];
  __shared__ int wsum[4];
  __shared__ unsigned vals[8192];
  __shared__ unsigned short sorted[8192];
  const int b = blockIdx.x;
  const int ebase = bucket_base[b];
  const int ecnt = bucket_base[b + 1] - ebase;
  const int t = threadIdx.x;
  hist[t] = 0;
  __syncthreads();
  for (int j = t; j < ecnt; j += 256){
    const unsigned v = ebuf[ebase + j];
    vals[j] = v;
    atomicAdd(&hist[v >> 16], 1);
  }
  __syncthreads();
  const int ex = blockScan256Excl(hist[t], wsum);
  excl[t] = ex;
  cursor[t] = ex;
  const int node = b * 256 + t;
  if (node < n){
    row_ptr[node] = ebase + ex;
    const int c = hist[t];
    inv[node] = 1.0f / (float)(c > 0 ? c : 1);
  }
  if (b == nb - 1 && t == 0) row_ptr[n] = E;
  __syncthreads();
  for (int j = t; j < ecnt; j += 256){
    const unsigned v = vals[j];
    const int pos = atomicAdd(&cursor[v >> 16], 1);
    sorted[pos] = (unsigned short)(v & 0xFFFFu);
  }
  __syncthreads();
  for (int j = t; j < ecnt; j += 256)
    csr[ebase + j] = sorted[j];
}

// ---------------- fp32 -> bf16 table convert ----------------
__global__ __launch_bounds__(256) void k_cvt(const float* __restrict__ in,
                                             unsigned short* __restrict__ out, int total){
  const int i = (blockIdx.x * 256 + threadIdx.x) * 4;
  if (i >= total) return;
  const float4 v = *(const float4*)&in[i];
  ushort2 a, b;
  a.x = bf16_rn(v.x); a.y = bf16_rn(v.y);
  b.x = bf16_rn(v.z); b.y = bf16_rn(v.w);
  *(ushort2*)&out[i] = a;
  *(ushort2*)&out[i + 2] = b;
}

// ---------------- mean aggregation: bf16 gather, fp32 accumulate, bf16 out ----------------
__global__ __launch_bounds__(256) void k_aggb(const unsigned short* __restrict__ featb,
                                              const unsigned short* __restrict__ csr,
                                              const int* __restrict__ row_ptr,
                                              const float* __restrict__ inv_cnt,
                                              unsigned short* __restrict__ outb, int n){
  const int lane = threadIdx.x & 63;
  const int node = (blockIdx.x * blockDim.x + threadIdx.x) >> 6;
  if (node >= n) return;
  const int beg = row_ptr[node];
  const int end = row_ptr[node + 1];
  const unsigned* __restrict__ fb = (const unsigned*)featb;   // [node][64]

  float ax0=0.f, ay0=0.f, ax1=0.f, ay1=0.f, ax2=0.f, ay2=0.f, ax3=0.f, ay3=0.f;
  float ax4=0.f, ay4=0.f, ax5=0.f, ay5=0.f, ax6=0.f, ay6=0.f, ax7=0.f, ay7=0.f;

  int j = beg;
  for (; j + 8 <= end; j += 8){
    const int s0 = csr[j+0], s1 = csr[j+1], s2 = csr[j+2], s3 = csr[j+3];
    const int s4 = csr[j+4], s5 = csr[j+5], s6 = csr[j+6], s7 = csr[j+7];
    const unsigned u0 = fb[(size_t)s0 * 64 + lane];
    const unsigned u1 = fb[(size_t)s1 * 64 + lane];
    const unsigned u2 = fb[(size_t)s2 * 64 + lane];
    const unsigned u3 = fb[(size_t)s3 * 64 + lane];
    const unsigned u4 = fb[(size_t)s4 * 64 + lane];
    const unsigned u5 = fb[(size_t)s5 * 64 + lane];
    const unsigned u6 = fb[(size_t)s6 * 64 + lane];
    const unsigned u7 = fb[(size_t)s7 * 64 + lane];
    ax0 += __uint_as_float(u0 << 16); ay0 += __uint_as_float(u0 & 0xFFFF0000u);
    ax1 += __uint_as_float(u1 << 16); ay1 += __uint_as_float(u1 & 0xFFFF0000u);
    ax2 += __uint_as_float(u2 << 16); ay2 += __uint_as_float(u2 & 0xFFFF0000u);
    ax3 += __uint_as_float(u3 << 16); ay3 += __uint_as_float(u3 & 0xFFFF0000u);
    ax4 += __uint_as_float(u4 << 16); ay4 += __uint_as_float(u4 & 0xFFFF0000u);
    ax5 += __uint_as_float(u5 << 16); ay5 += __uint_as_float(u5 & 0xFFFF0000u);
    ax6 += __uint_as_float(u6 << 16); ay6 += __uint_as_float(u6 & 0xFFFF0000u);
    ax7 += __uint_as_float(u7 << 16); ay7 += __uint_as_float(u7 & 0xFFFF0000u);
  }
  if (j + 4 <= end){
    const int s0 = csr[j+0], s1 = csr[j+1], s2 = csr[j+2], s3 = csr[j+3];
    const unsigned u0 = fb[(size_t)s0 * 64 + lane];
    const unsigned u1 = fb[(size_t)s1 * 64 + lane];
    const unsigned u2 = fb[(size_t)s2 * 64 + lane];
    const unsigned u3 = fb[(size_t)s3 * 64 + lane];
    ax0 += __uint_as_float(u0 << 16); ay0 += __uint_as_float(u0 & 0xFFFF0000u);
    ax1 += __uint_as_float(u1 << 16); ay1 += __uint_as_float(u1 & 0xFFFF0000u);
    ax2 += __uint_as_float(u2 << 16); ay2 += __uint_as_float(u2 & 0xFFFF0000u);
    ax3 += __uint_as_float(u3 << 16); ay3 += __uint_as_float(u3 & 0xFFFF0000u);
    j += 4;
  }
  for (; j < end; ++j){
    const int s = csr[j];
    const unsigned u = fb[(size_t)s * 64 + lane];
    ax4 += __uint_as_float(u << 16); ay4 += __uint_as_float(u & 0xFFFF0000u);
  }

  const float ic = inv_cnt[node];
  const float ox = (((ax0 + ax1) + (ax2 + ax3)) + ((ax4 + ax5) + (ax6 + ax7))) * ic;
  const float oy = (((ay0 + ay1) + (ay2 + ay3)) + ((ay4 + ay5) + (ay6 + ay7))) * ic;
  const unsigned packed = (unsigned)bf16_rn(ox) | ((unsigned)bf16_rn(oy) << 16);
  ((unsigned*)outb)[(size_t)node * 64 + lane] = packed;
}

// ---------------- weight pack + bf16 hi/lo split, FRAGMENT-MAJOR ----------------
__global__ void k_wcs(const float* __restrict__ wl, const float* __restrict__ wr,
                      short* __restrict__ bfr){
  int id = blockIdx.x * 256 + threadIdx.x;
  if (id >= 128 * 256) return;
  int c = id >> 8, k = id & 255;
  float w = (k < 128) ? wl[c * 128 + k] : wr[c * 128 + (k - 128)];
  unsigned short h = bf16_rn(w);
  float hf = __uint_as_float((unsigned)h << 16);
  unsigned short l = bf16_rn(w - hf);
  const int nt = c >> 4, mrow = c & 15;
  const int ks = k >> 5, kgrp = (k >> 3) & 3, j = k & 7;
  const int lane = kgrp * 16 + mrow;
  const size_t fbase = (size_t)((ks * 8 + nt) * 2) * 512 + lane * 8 + j;
  bfr[fbase] = (short)h;
  bfr[fbase + 512] = (short)l;
}

// ---------------- MFMA GEMM: out = prelu([A0|A1] @ W^T + b) ----------------
// A0,A1 bf16 [n][128]; A-tile staged in LDS (XOR-swizzled), W split hi/lo.
// D = A*Bh + A*Bl.  Either fp32 or bf16 output (or both).
__global__ __launch_bounds__(256) void k_gemm_mfma(const unsigned short* __restrict__ A0b,
                                                   const unsigned short* __restrict__ A1b,
                                                   const short* __restrict__ bfr,
                                                   const float* __restrict__ bias,
                                                   const float* __restrict__ alpha_p,
                                                   float* __restrict__ outf,            // may be null
                                                   unsigned short* __restrict__ outb16, // may be null
                                                   int n){
  __shared__ short aT[2][64 * 128];   // 2 tables x 64 rows x 256B, swizzled
  const int t = threadIdx.x;
  const int lane = t & 63;
  const int wv = t >> 6;
  const int nodeBase = blockIdx.x * 64;

  // stage both A tables; coalesced global reads, swizzled LDS writes
  #pragma unroll
  for (int tab = 0; tab < 2; ++tab){
    const unsigned short* __restrict__ src = tab ? A1b : A0b;
    #pragma unroll
    for (int it = 0; it < 4; ++it){
      const int chunk = it * 256 + t;       // 1024 chunks of 16B
      const int row = chunk >> 4;
      const int slot = chunk & 15;
      int gr = nodeBase + row; if (gr > n - 1) gr = n - 1;
      const uint4 v = *(const uint4*)&src[(size_t)gr * 128 + slot * 8];
      const int sslot = slot ^ (row & 7);
      *(uint4*)((char*)&aT[tab][0] + row * 256 + sslot * 16) = v;
    }
  }
  __syncthreads();

  const short8* __restrict__ Bf = (const short8*)bfr;
  const int mrow = lane & 15;
  const int kgrp = lane >> 4;
  const int arow = wv * 16 + mrow;

  f32x4 acc[8];
  #pragma unroll
  for (int i = 0; i < 8; ++i) acc[i] = (f32x4){0.f, 0.f, 0.f, 0.f};

  #pragma unroll
  for (int ks = 0; ks < 8; ++ks){
    const int tab = ks >> 2;
    const int slot_r = (ks & 3) * 4 + kgrp;
    const short8 aF = *(const short8*)((const char*)&aT[tab][0] + arow * 256 + (slot_r ^ (arow & 7)) * 16);

    short8 bh[8], bl[8];
    const int fb = ks * 16;
    #pragma unroll
    for (int nt = 0; nt < 8; ++nt){
      bh[nt] = Bf[(size_t)(fb + nt * 2 + 0) * 64 + lane];
      bl[nt] = Bf[(size_t)(fb + nt * 2 + 1) * 64 + lane];
    }
    #pragma unroll
    for (int nt = 0; nt < 8; ++nt){
      mfma_bf16(acc[nt], aF, bh[nt]);
      mfma_bf16(acc[nt], aF, bl[nt]);
    }
  }

  const float alpha = *alpha_p;
  const int nodeQ = nodeBase + wv * 16 + kgrp * 4;
  #pragma unroll
  for (int nt = 0; nt < 8; ++nt){
    const int col = nt * 16 + mrow;
    const float bv = bias[col];
    #pragma unroll
    for (int j = 0; j < 4; ++j){
      const int onode = nodeQ + j;
      if (onode < n){
        float v = acc[nt][j] + bv;
        v = fmaxf(v, 0.f) + alpha * fminf(v, 0.f);
        if (outf)   outf[(size_t)onode * 128 + col] = v;
        if (outb16) outb16[(size_t)onode * 128 + col] = bf16_rn(v);
      }
    }
  }
}

// ---------------- layer-3 fusion ----------------
__global__ void k_u(const float* __restrict__ w3l, const float* __restrict__ w3r,
                    const float* __restrict__ b3, const float* __restrict__ wp,
                    const float* __restrict__ bp, float* __restrict__ u){
  int k = threadIdx.x;
  float sl = 0.f, sr = 0.f;
  for (int o = 0; o < 64; ++o){
    float w = wp[o];
    sl = fmaf(w, w3l[o * 128 + k], sl);
    sr = fmaf(w, w3r[o * 128 + k], sr);
  }
  u[k] = sl; u[128 + k] = sr;
  if (k == 0){
    float c = bp[0];
    for (int o = 0; o < 64; ++o) c = fmaf(wp[o], b3[o], c);
    u[256] = c;
  }
}

__global__ __launch_bounds__(256) void k_dot(const float* __restrict__ h,
                                             const float* __restrict__ u,
                                             float* __restrict__ s,
                                             float* __restrict__ partial, int n){
  const int lane = threadIdx.x & 63;
  const int i = blockIdx.x * 4 + (threadIdx.x >> 6);
  if (i >= n) return;
  const float2 hv  = *(const float2*)&h[(size_t)i * 128 + lane * 2];
  const float2 ulv = *(const float2*)&u[lane * 2];
  const float2 urv = *(const float2*)&u[128 + lane * 2];
  float sv = hv.x * ulv.x + hv.y * ulv.y;
  float tv = hv.x * urv.x + hv.y * urv.y;
  #pragma unroll
  for (int off = 32; off > 0; off >>= 1){
    sv += __shfl_down(sv, off);
    tv += __shfl_down(tv, off);
  }
  if (lane == 0){ s[i] = sv; partial[i] = tv + u[256]; }
}

__global__ __launch_bounds__(256) void k_final(const float* __restrict__ s, const float* __restrict__ partial,
                        const unsigned short* __restrict__ csr, const int* __restrict__ row_ptr,
                        const float* __restrict__ inv_cnt, float* __restrict__ out, int n){
  const int t = blockIdx.x * blockDim.x + threadIdx.x;
  const int node = t >> 2;
  const int sub = t & 3;
  if (node >= n) return;
  const int b = row_ptr[node], e = row_ptr[node + 1];
  float a0 = 0.f, a1 = 0.f;
  int j = b + sub;
  for (; j + 4 < e; j += 8){
    a0 += s[csr[j]];
    a1 += s[csr[j + 4]];
  }
  if (j < e) a0 += s[csr[j]];
  float acc = a0 + a1;
  acc += __shfl_down(acc, 1);
  acc += __shfl_down(acc, 2);
  if (sub == 0) out[node] = acc * inv_cnt[node] + partial[node];
}

// ---------------- launch ----------------
extern "C" void kernel_launch(void* const* d_in, const int* in_sizes, int n_in,
                              void* d_out, int out_size, void* d_ws, size_t ws_size,
                              hipStream_t stream){
  const float* x   = (const float*)d_in[0];
  const int*   ei  = (const int*)d_in[1];
  const float* w1l = (const float*)d_in[2];
  const float* w1r = (const float*)d_in[3];
  const float* b1  = (const float*)d_in[4];
  const float* w2l = (const float*)d_in[5];
  const float* w2r = (const float*)d_in[6];
  const float* b2  = (const float*)d_in[7];
  const float* w3l = (const float*)d_in[8];
  const float* w3r = (const float*)d_in[9];
  const float* b3  = (const float*)d_in[10];
  const float* ap  = (const float*)d_in[11];
  const float* wp  = (const float*)d_in[12];
  const float* bp  = (const float*)d_in[13];

  const int n = out_size;              // 50000 nodes
  const int E = in_sizes[1] / 2;       // 800000 edges
  const int* srcI = ei;
  const int* dstI = ei + E;

  const int ntiles = (E + 2047) / 2048;
  const int nb = (n + 255) >> 8;       // 196 buckets

  char* base = (char*)d_ws;
  size_t off = 0;
  auto take = [&](size_t bytes) -> char* {
    off = (off + 255) & ~(size_t)255;
    char* p = base + off;
    off += bytes;
    return p;
  };
  int*      blk_hist = (int*)   take((size_t)nb * ntiles * 4);
  int*      tot      = (int*)   take((size_t)nb * 4);
  int*      bbase    = (int*)   take(((size_t)nb + 1) * 4);
  unsigned* ebuf     = (unsigned*)take((size_t)E * 4);
  int*      rowp     = (int*)   take(((size_t)n + 1) * 4);
  float*    inv      = (float*) take((size_t)n * 4);
  unsigned short* csr = (unsigned short*)take((size_t)E * 2);
  unsigned short* B1b = (unsigned short*)take((size_t)n * 128 * 2);  // agg out, bf16
  float*    B2   = (float*)take((size_t)n * 128 * 4);                // h2, fp32
  unsigned short* xb  = (unsigned short*)take((size_t)n * 128 * 2);
  unsigned short* h1b = (unsigned short*)take((size_t)n * 128 * 2);
  float*    sbuf = (float*)take((size_t)n * 4);
  float*    pbuf = (float*)take((size_t)n * 4);
  float*    u    = (float*)take(257 * 4);
  short*    bfr  = (short*)take((size_t)128 * 512 * 2);
  (void)ws_size; (void)n_in;

  // CSR build: counting sort, no global atomics, coalesced writes
  k_bcount<<<ntiles, 256, 0, stream>>>(dstI, E, nb, ntiles, blk_hist);
  k_bscan <<<nb,     256, 0, stream>>>(blk_hist, nb, ntiles, tot);
  k_btot  <<<1,      256, 0, stream>>>(tot, nb, bbase);
  k_bscat <<<ntiles, 256, 0, stream>>>(srcI, dstI, E, nb, ntiles, blk_hist, bbase, ebuf);
  k_csrfin<<<nb,     256, 0, stream>>>(ebuf, bbase, n, E, nb, rowp, inv, csr);

  // bf16 feature table for gathers + GEMM A
  k_cvt<<<(n * 128 / 4 + 255) / 256, 256, 0, stream>>>(x, xb, n * 128);

  const int aggGrid  = (n * 64 + 255) / 256;
  const int gemmGrid = (n + 63) / 64;

  // layer 1: h1 = prelu([agg(x)|x] @ W1 + b1)  -> bf16 only
  k_aggb     <<<aggGrid, 256, 0, stream>>>(xb, csr, rowp, inv, B1b, n);
  k_wcs      <<<128, 256, 0, stream>>>(w1l, w1r, bfr);
  k_gemm_mfma<<<gemmGrid, 256, 0, stream>>>(B1b, xb, bfr, b1, ap, (float*)nullptr, h1b, n);

  // layer 2: h2 = prelu([agg(h1)|h1] @ W2 + b2) -> fp32 only
  k_aggb     <<<aggGrid, 256, 0, stream>>>(h1b, csr, rowp, inv, B1b, n);
  k_wcs      <<<128, 256, 0, stream>>>(w2l, w2r, bfr);
  k_gemm_mfma<<<gemmGrid, 256, 0, stream>>>(B1b, h1b, bfr, b2, ap, B2, (unsigned short*)nullptr, n);

  // layer 3 + head, fused via u_l = wp@w3l, u_r = wp@w3r
  k_u    <<<1, 128, 0, stream>>>(w3l, w3r, b3, wp, bp, u);
  k_dot  <<<(n + 3) / 4, 256, 0, stream>>>(B2, u, sbuf, pbuf, n);
  k_final<<<(n * 4 + 255) / 256, 256, 0, stream>>>(sbuf, pbuf, csr, rowp, inv, (float*)d_out, n);
}